// Round 2
// baseline (3784.797 us; speedup 1.0000x reference)
//
#include <hip/hip_runtime.h>
#include <cstdint>
#include <cstddef>

#define NFEAT 512
#define NH1   256
#define NH2   128

// ---------------- degree / dinv ----------------
__global__ void k_fill1(float* __restrict__ p, int n) {
    int i = blockIdx.x * blockDim.x + threadIdx.x;
    if (i < n) p[i] = 1.0f;   // self-loop contributes 1 to every node's degree
}

__global__ void k_deg(const int* __restrict__ dst, float* __restrict__ deg, int E) {
    int i = blockIdx.x * blockDim.x + threadIdx.x;
    int stride = gridDim.x * blockDim.x;
    for (int e = i; e < E; e += stride)
        atomicAdd(&deg[dst[e]], 1.0f);
}

__global__ void k_rsqrt(float* __restrict__ p, int n) {
    int i = blockIdx.x * blockDim.x + threadIdx.x;
    if (i < n) p[i] = rsqrtf(p[i]);   // deg >= 1 always (self-loop), matches where(deg>0)
}

// ---------------- fp32 tiled GEMM: C[M,N] = A[M,K] * B[K,N] ----------------
// 128x128 tile, BK=16, 256 threads, 8x8 microtile per thread.
__global__ __launch_bounds__(256) void gemm_f32(
    const float* __restrict__ A, const float* __restrict__ B, float* __restrict__ C,
    int M, int N, int K) {
    __shared__ float As[16][132];   // transposed: As[k][m], +4 pad keeps 16B align
    __shared__ float Bs[16][132];   // Bs[k][n]

    const int t  = threadIdx.x;
    const int tx = t & 15, ty = t >> 4;
    const int row0 = blockIdx.y * 128, col0 = blockIdx.x * 128;

    // A-tile staging: 128 rows x 16 k = 512 float4; thread loads rows (t>>2) and (t>>2)+64
    const int am = t >> 2;          // 0..63
    const int ak = (t & 3) * 4;     // 0,4,8,12
    // B-tile staging: 16 rows x 128 = 512 float4; thread loads rows (t>>5) and (t>>5)+8
    const int br = t >> 5;          // 0..7
    const int bc = (t & 31) * 4;    // 0..124

    float acc[8][8] = {};

    for (int k0 = 0; k0 < K; k0 += 16) {
        float4 a0 = make_float4(0.f, 0.f, 0.f, 0.f);
        float4 a1 = make_float4(0.f, 0.f, 0.f, 0.f);
        const int r1 = row0 + am, r2 = row0 + am + 64;
        if (r1 < M) a0 = *(const float4*)&A[(size_t)r1 * K + k0 + ak];
        if (r2 < M) a1 = *(const float4*)&A[(size_t)r2 * K + k0 + ak];
        const float4 b0 = *(const float4*)&B[(size_t)(k0 + br)     * N + col0 + bc];
        const float4 b1 = *(const float4*)&B[(size_t)(k0 + br + 8) * N + col0 + bc];

        __syncthreads();   // previous tile's compute done before overwrite
        As[ak + 0][am] = a0.x; As[ak + 1][am] = a0.y; As[ak + 2][am] = a0.z; As[ak + 3][am] = a0.w;
        As[ak + 0][am + 64] = a1.x; As[ak + 1][am + 64] = a1.y; As[ak + 2][am + 64] = a1.z; As[ak + 3][am + 64] = a1.w;
        *(float4*)&Bs[br][bc]     = b0;
        *(float4*)&Bs[br + 8][bc] = b1;
        __syncthreads();

#pragma unroll
        for (int k = 0; k < 16; ++k) {
            const float4 av0 = *(const float4*)&As[k][ty * 4];
            const float4 av1 = *(const float4*)&As[k][ty * 4 + 64];
            const float4 bv0 = *(const float4*)&Bs[k][tx * 4];
            const float4 bv1 = *(const float4*)&Bs[k][tx * 4 + 64];
            const float a[8] = {av0.x, av0.y, av0.z, av0.w, av1.x, av1.y, av1.z, av1.w};
            const float b[8] = {bv0.x, bv0.y, bv0.z, bv0.w, bv1.x, bv1.y, bv1.z, bv1.w};
#pragma unroll
            for (int i = 0; i < 8; ++i)
#pragma unroll
                for (int j = 0; j < 8; ++j)
                    acc[i][j] = fmaf(a[i], b[j], acc[i][j]);
        }
    }

#pragma unroll
    for (int i = 0; i < 8; ++i) {
        const int row = row0 + (i < 4 ? ty * 4 + i : 64 + ty * 4 + (i - 4));
        if (row >= M) continue;
        float* cp = &C[(size_t)row * N + col0];
        *(float4*)&cp[tx * 4]      = make_float4(acc[i][0], acc[i][1], acc[i][2], acc[i][3]);
        *(float4*)&cp[64 + tx * 4] = make_float4(acc[i][4], acc[i][5], acc[i][6], acc[i][7]);
    }
}

// ---------------- aggregation ----------------
// Init agg with self-loop term + bias (atomics then just accumulate edges):
// agg[i,f] = h[i,f] * dinv[i]^2 + bias[f]
template <int F>
__global__ void k_self_init(const float* __restrict__ h, const float* __restrict__ dinv,
                            const float* __restrict__ bias, float* __restrict__ agg, int N) {
    int idx  = blockIdx.x * blockDim.x + threadIdx.x;
    int node = idx / (F / 4);
    int q    = idx % (F / 4);
    if (node >= N) return;
    float w = dinv[node];
    w = w * w;
    const float4 v = *(const float4*)&h[(size_t)node * F + q * 4];
    const float4 b = *(const float4*)&bias[q * 4];
    float4 r;
    r.x = fmaf(v.x, w, b.x); r.y = fmaf(v.y, w, b.y);
    r.z = fmaf(v.z, w, b.z); r.w = fmaf(v.w, w, b.w);
    *(float4*)&agg[(size_t)node * F + q * 4] = r;
}

// One wave per edge (grid-stride): coalesced row gather + per-lane atomics.
template <int F>
__global__ void k_scatter(const int* __restrict__ src, const int* __restrict__ dst,
                          const float* __restrict__ dinv, const float* __restrict__ h,
                          float* __restrict__ agg, int E) {
    const int gid  = blockIdx.x * blockDim.x + threadIdx.x;
    const int wave = gid >> 6;
    const int lane = gid & 63;
    const int nw   = (gridDim.x * blockDim.x) >> 6;
    for (int e = wave; e < E; e += nw) {
        const int s = src[e];
        const int d = dst[e];
        const float w = dinv[s] * dinv[d];
        if (F == 256) {
            const float4 v = *(const float4*)&h[(size_t)s * F + lane * 4];
            float* o = &agg[(size_t)d * F + lane * 4];
            atomicAdd(o + 0, v.x * w);
            atomicAdd(o + 1, v.y * w);
            atomicAdd(o + 2, v.z * w);
            atomicAdd(o + 3, v.w * w);
        } else {
            const float2 v = *(const float2*)&h[(size_t)s * F + lane * 2];
            float* o = &agg[(size_t)d * F + lane * 2];
            atomicAdd(o + 0, v.x * w);
            atomicAdd(o + 1, v.y * w);
        }
    }
}

__global__ void k_relu4(float4* __restrict__ p, int n4) {
    int i = blockIdx.x * blockDim.x + threadIdx.x;
    if (i >= n4) return;
    float4 v = p[i];
    v.x = fmaxf(v.x, 0.f); v.y = fmaxf(v.y, 0.f);
    v.z = fmaxf(v.z, 0.f); v.w = fmaxf(v.w, 0.f);
    p[i] = v;
}

extern "C" void kernel_launch(void* const* d_in, const int* in_sizes, int n_in,
                              void* d_out, int out_size, void* d_ws, size_t ws_size,
                              hipStream_t stream) {
    const float* x   = (const float*)d_in[0];
    const int*   ei  = (const int*)d_in[1];     // harness delivers integer inputs as int32
    const float* W1  = (const float*)d_in[2];
    const float* b1  = (const float*)d_in[3];
    const float* W2  = (const float*)d_in[4];
    const float* b2  = (const float*)d_in[5];
    float*       out = (float*)d_out;

    const int N = in_sizes[0] / NFEAT;   // 50000
    const int E = in_sizes[1] / 2;       // 800000
    const int* srcp = ei;
    const int* dstp = ei + E;

    // workspace layout (floats): dinv | bufA (N*256) | bufB (N*256)
    // h -> bufA ; agg1/h1 -> bufB ; h2 -> bufA (aliases dead h). Peak ~103 MB.
    float* ws   = (float*)d_ws;
    float* dinv = ws;
    float* bufA = ws + 51200;                    // 16B-aligned, > N
    float* bufB = bufA + (size_t)N * NH1;

    float* h    = bufA;
    float* agg1 = bufB;
    float* h2   = bufA;

    // ---- degrees -> dinv ----
    k_fill1<<<(N + 255) / 256, 256, 0, stream>>>(dinv, N);
    k_deg<<<1024, 256, 0, stream>>>(dstp, dinv, E);
    k_rsqrt<<<(N + 255) / 256, 256, 0, stream>>>(dinv, N);

    // ---- layer 1: h = x@W1 ; agg1 = A_hat*h + b1 ; relu ----
    {
        dim3 g(NH1 / 128, (N + 127) / 128);
        gemm_f32<<<g, 256, 0, stream>>>(x, W1, h, N, NH1, NFEAT);
    }
    {
        int threads = N * (NH1 / 4);
        k_self_init<NH1><<<(threads + 255) / 256, 256, 0, stream>>>(h, dinv, b1, agg1, N);
    }
    k_scatter<NH1><<<2048, 256, 0, stream>>>(srcp, dstp, dinv, h, agg1, E);
    {
        int n4 = N * NH1 / 4;
        k_relu4<<<(n4 + 255) / 256, 256, 0, stream>>>((float4*)agg1, n4);
    }

    // ---- layer 2: h2 = h1@W2 ; out = A_hat*h2 + b2 ----
    {
        dim3 g(NH2 / 128, (N + 127) / 128);
        gemm_f32<<<g, 256, 0, stream>>>(agg1, W2, h2, N, NH2, NH1);
    }
    {
        int threads = N * (NH2 / 4);
        k_self_init<NH2><<<(threads + 255) / 256, 256, 0, stream>>>(h2, dinv, b2, out, N);
    }
    k_scatter<NH2><<<2048, 256, 0, stream>>>(srcp, dstp, dinv, h2, out, E);
}

// Round 3
// 790.630 us; speedup vs baseline: 4.7871x; 4.7871x over previous
//
#include <hip/hip_runtime.h>
#include <cstdint>
#include <cstddef>

#define NFEAT 512
#define NH1   256
#define NH2   128

// ---------------- CSR build ----------------
__global__ void k_zero_int(int* __restrict__ p, int n) {
    int i = blockIdx.x * blockDim.x + threadIdx.x;
    if (i < n) p[i] = 0;
}

__global__ void k_deg_int(const int* __restrict__ dst, int* __restrict__ degi, int E) {
    int i = blockIdx.x * blockDim.x + threadIdx.x;
    int stride = gridDim.x * blockDim.x;
    for (int e = i; e < E; e += stride)
        atomicAdd(&degi[dst[e]], 1);
}

// dinv[i] = rsqrt(degi[i] + 1)   (+1 = self-loop)
__global__ void k_dinv(const int* __restrict__ degi, float* __restrict__ dinv, int n) {
    int i = blockIdx.x * blockDim.x + threadIdx.x;
    if (i < n) dinv[i] = rsqrtf((float)(degi[i] + 1));
}

// Single-workgroup exclusive scan: row_start[i] = sum(degi[0..i)), row_start[N] = E.
// Also initializes cursor[i] = row_start[i].
__global__ __launch_bounds__(1024) void k_scan(const int* __restrict__ degi,
                                               int* __restrict__ row_start,
                                               int* __restrict__ cursor, int N) {
    __shared__ int smem[1024];
    __shared__ int carry_s;
    if (threadIdx.x == 0) carry_s = 0;
    __syncthreads();
    for (int base = 0; base < N; base += 1024) {
        const int i = base + (int)threadIdx.x;
        const int v = (i < N) ? degi[i] : 0;
        smem[threadIdx.x] = v;
        __syncthreads();
#pragma unroll
        for (int off = 1; off < 1024; off <<= 1) {
            int t = (threadIdx.x >= (unsigned)off) ? smem[threadIdx.x - off] : 0;
            __syncthreads();
            smem[threadIdx.x] += t;
            __syncthreads();
        }
        const int incl = smem[threadIdx.x] + carry_s;
        if (i < N) {
            const int excl = incl - v;
            row_start[i] = excl;
            cursor[i]    = excl;
        }
        __syncthreads();
        if (threadIdx.x == 1023) carry_s = incl;
        __syncthreads();
    }
    if (threadIdx.x == 0) row_start[N] = carry_s;
}

__global__ void k_build(const int* __restrict__ src, const int* __restrict__ dst,
                        int* __restrict__ cursor, int* __restrict__ csr_src, int E) {
    int i = blockIdx.x * blockDim.x + threadIdx.x;
    int stride = gridDim.x * blockDim.x;
    for (int e = i; e < E; e += stride) {
        int pos = atomicAdd(&cursor[dst[e]], 1);
        csr_src[pos] = src[e];
    }
}

// ---------------- fp32 tiled GEMM: C[M,N] = A[M,K] * B[K,N] ----------------
// 128x128 tile, BK=16, 256 threads, 8x8 microtile per thread.
__global__ __launch_bounds__(256) void gemm_f32(
    const float* __restrict__ A, const float* __restrict__ B, float* __restrict__ C,
    int M, int N, int K) {
    __shared__ float As[16][132];   // transposed: As[k][m]
    __shared__ float Bs[16][132];   // Bs[k][n]

    const int t  = threadIdx.x;
    const int tx = t & 15, ty = t >> 4;
    const int row0 = blockIdx.y * 128, col0 = blockIdx.x * 128;

    const int am = t >> 2;          // 0..63
    const int ak = (t & 3) * 4;     // 0,4,8,12
    const int br = t >> 5;          // 0..7
    const int bc = (t & 31) * 4;    // 0..124

    float acc[8][8] = {};

    for (int k0 = 0; k0 < K; k0 += 16) {
        float4 a0 = make_float4(0.f, 0.f, 0.f, 0.f);
        float4 a1 = make_float4(0.f, 0.f, 0.f, 0.f);
        const int r1 = row0 + am, r2 = row0 + am + 64;
        if (r1 < M) a0 = *(const float4*)&A[(size_t)r1 * K + k0 + ak];
        if (r2 < M) a1 = *(const float4*)&A[(size_t)r2 * K + k0 + ak];
        const float4 b0 = *(const float4*)&B[(size_t)(k0 + br)     * N + col0 + bc];
        const float4 b1 = *(const float4*)&B[(size_t)(k0 + br + 8) * N + col0 + bc];

        __syncthreads();
        As[ak + 0][am] = a0.x; As[ak + 1][am] = a0.y; As[ak + 2][am] = a0.z; As[ak + 3][am] = a0.w;
        As[ak + 0][am + 64] = a1.x; As[ak + 1][am + 64] = a1.y; As[ak + 2][am + 64] = a1.z; As[ak + 3][am + 64] = a1.w;
        *(float4*)&Bs[br][bc]     = b0;
        *(float4*)&Bs[br + 8][bc] = b1;
        __syncthreads();

#pragma unroll
        for (int k = 0; k < 16; ++k) {
            const float4 av0 = *(const float4*)&As[k][ty * 4];
            const float4 av1 = *(const float4*)&As[k][ty * 4 + 64];
            const float4 bv0 = *(const float4*)&Bs[k][tx * 4];
            const float4 bv1 = *(const float4*)&Bs[k][tx * 4 + 64];
            const float a[8] = {av0.x, av0.y, av0.z, av0.w, av1.x, av1.y, av1.z, av1.w};
            const float b[8] = {bv0.x, bv0.y, bv0.z, bv0.w, bv1.x, bv1.y, bv1.z, bv1.w};
#pragma unroll
            for (int i = 0; i < 8; ++i)
#pragma unroll
                for (int j = 0; j < 8; ++j)
                    acc[i][j] = fmaf(a[i], b[j], acc[i][j]);
        }
    }

#pragma unroll
    for (int i = 0; i < 8; ++i) {
        const int row = row0 + (i < 4 ? ty * 4 + i : 64 + ty * 4 + (i - 4));
        if (row >= M) continue;
        float* cp = &C[(size_t)row * N + col0];
        *(float4*)&cp[tx * 4]      = make_float4(acc[i][0], acc[i][1], acc[i][2], acc[i][3]);
        *(float4*)&cp[64 + tx * 4] = make_float4(acc[i][4], acc[i][5], acc[i][6], acc[i][7]);
    }
}

// ---------------- CSR gather aggregation ----------------
// One wave per destination node. Lane holds F/64 contiguous floats of the row.
// out[d] = relu?( h[d]*dinv[d]^2 + bias + sum_{e: dst=d} h[src_e]*dinv[src_e]*dinv[d] )
template <int F, bool RELU>
__global__ __launch_bounds__(256) void k_gather(
    const int* __restrict__ row_start, const int* __restrict__ csr_src,
    const float* __restrict__ dinv, const float* __restrict__ h,
    const float* __restrict__ bias, float* __restrict__ outp, int N) {
    const int gid  = blockIdx.x * blockDim.x + threadIdx.x;
    const int node = gid >> 6;
    const int lane = gid & 63;
    if (node >= N) return;

    const float wd = dinv[node];
    const int jb = row_start[node];
    const int je = row_start[node + 1];

    if (F == 256) {
        const float4 hv = *(const float4*)&h[(size_t)node * F + lane * 4];
        const float4 bv = *(const float4*)&bias[lane * 4];
        const float ws = wd * wd;
        float4 acc;
        acc.x = fmaf(hv.x, ws, bv.x); acc.y = fmaf(hv.y, ws, bv.y);
        acc.z = fmaf(hv.z, ws, bv.z); acc.w = fmaf(hv.w, ws, bv.w);
        for (int j = jb; j < je; ++j) {
            const int s = csr_src[j];
            const float w = dinv[s] * wd;
            const float4 v = *(const float4*)&h[(size_t)s * F + lane * 4];
            acc.x = fmaf(v.x, w, acc.x); acc.y = fmaf(v.y, w, acc.y);
            acc.z = fmaf(v.z, w, acc.z); acc.w = fmaf(v.w, w, acc.w);
        }
        if (RELU) {
            acc.x = fmaxf(acc.x, 0.f); acc.y = fmaxf(acc.y, 0.f);
            acc.z = fmaxf(acc.z, 0.f); acc.w = fmaxf(acc.w, 0.f);
        }
        *(float4*)&outp[(size_t)node * F + lane * 4] = acc;
    } else {
        const float2 hv = *(const float2*)&h[(size_t)node * F + lane * 2];
        const float2 bv = *(const float2*)&bias[lane * 2];
        const float ws = wd * wd;
        float2 acc;
        acc.x = fmaf(hv.x, ws, bv.x); acc.y = fmaf(hv.y, ws, bv.y);
        for (int j = jb; j < je; ++j) {
            const int s = csr_src[j];
            const float w = dinv[s] * wd;
            const float2 v = *(const float2*)&h[(size_t)s * F + lane * 2];
            acc.x = fmaf(v.x, w, acc.x); acc.y = fmaf(v.y, w, acc.y);
        }
        if (RELU) { acc.x = fmaxf(acc.x, 0.f); acc.y = fmaxf(acc.y, 0.f); }
        *(float2*)&outp[(size_t)node * F + lane * 2] = acc;
    }
}

extern "C" void kernel_launch(void* const* d_in, const int* in_sizes, int n_in,
                              void* d_out, int out_size, void* d_ws, size_t ws_size,
                              hipStream_t stream) {
    const float* x   = (const float*)d_in[0];
    const int*   ei  = (const int*)d_in[1];
    const float* W1  = (const float*)d_in[2];
    const float* b1  = (const float*)d_in[3];
    const float* W2  = (const float*)d_in[4];
    const float* b2  = (const float*)d_in[5];
    float*       out = (float*)d_out;

    const int N = in_sizes[0] / NFEAT;   // 50000
    const int E = in_sizes[1] / 2;       // 800000
    const int* srcp = ei;
    const int* dstp = ei + E;

    // workspace layout (all 16B-aligned; N=50000 -> N ints = 200000 B, /16 ok)
    char* wsb = (char*)d_ws;
    int*   degi      = (int*)wsb;                       wsb += (size_t)N * 4;
    int*   row_start = (int*)wsb;                       wsb += (size_t)(N + 4) * 4;
    int*   cursor    = (int*)wsb;                       wsb += (size_t)N * 4;
    int*   csr_src   = (int*)wsb;                       wsb += (size_t)E * 4;
    float* dinv      = (float*)wsb;                     wsb += (size_t)N * 4;
    float* bufA      = (float*)wsb;                     wsb += (size_t)N * NH1 * 4;
    float* bufB      = (float*)wsb;                     // N*NH1 floats

    float* h    = bufA;   // x@W1
    float* h1   = bufB;   // relu(A_hat h + b1)
    float* h2   = bufA;   // h1@W2 (aliases dead h)

    // ---- CSR build + dinv ----
    k_zero_int<<<(N + 255) / 256, 256, 0, stream>>>(degi, N);
    k_deg_int<<<1024, 256, 0, stream>>>(dstp, degi, E);
    k_dinv<<<(N + 255) / 256, 256, 0, stream>>>(degi, dinv, N);
    k_scan<<<1, 1024, 0, stream>>>(degi, row_start, cursor, N);
    k_build<<<1024, 256, 0, stream>>>(srcp, dstp, cursor, csr_src, E);

    // ---- layer 1: h = x@W1 ; h1 = relu(A_hat h + b1) ----
    {
        dim3 g(NH1 / 128, (N + 127) / 128);
        gemm_f32<<<g, 256, 0, stream>>>(x, W1, h, N, NH1, NFEAT);
    }
    {
        int total = N * 64;
        k_gather<NH1, true><<<(total + 255) / 256, 256, 0, stream>>>(
            row_start, csr_src, dinv, h, b1, h1, N);
    }

    // ---- layer 2: h2 = h1@W2 ; out = A_hat h2 + b2 ----
    {
        dim3 g(NH2 / 128, (N + 127) / 128);
        gemm_f32<<<g, 256, 0, stream>>>(h1, W2, h2, N, NH2, NH1);
    }
    {
        int total = N * 64;
        k_gather<NH2, false><<<(total + 255) / 256, 256, 0, stream>>>(
            row_start, csr_src, dinv, h2, b2, out, N);
    }
}

// Round 4
// 608.794 us; speedup vs baseline: 6.2169x; 1.2987x over previous
//
#include <hip/hip_runtime.h>
#include <cstdint>
#include <cstddef>

#define NFEAT 512
#define NH1   256
#define NH2   128

typedef __attribute__((ext_vector_type(8))) short short8;
typedef __attribute__((ext_vector_type(4))) float float4v;

__device__ __forceinline__ unsigned short f2bf(float f) {
    unsigned int u = __float_as_uint(f);
    u += 0x7fffu + ((u >> 16) & 1u);   // round-to-nearest-even
    return (unsigned short)(u >> 16);
}
__device__ __forceinline__ float bf2f(unsigned short u) {
    return __uint_as_float(((unsigned int)u) << 16);
}

__device__ __forceinline__ void load_lds16(const void* g, void* l) {
    __builtin_amdgcn_global_load_lds(
        (const __attribute__((address_space(1))) void*)g,
        (__attribute__((address_space(3))) void*)l, 16, 0, 0);
}

// ---------------- CSR build ----------------
__global__ void k_zero_int(int* __restrict__ p, int n) {
    int i = blockIdx.x * blockDim.x + threadIdx.x;
    if (i < n) p[i] = 0;
}

__global__ void k_deg_int(const int* __restrict__ dst, int* __restrict__ degi, int E) {
    int i = blockIdx.x * blockDim.x + threadIdx.x;
    int stride = gridDim.x * blockDim.x;
    for (int e = i; e < E; e += stride)
        atomicAdd(&degi[dst[e]], 1);
}

__global__ void k_dinv(const int* __restrict__ degi, float* __restrict__ dinv, int n) {
    int i = blockIdx.x * blockDim.x + threadIdx.x;
    if (i < n) dinv[i] = rsqrtf((float)(degi[i] + 1));   // +1 = self-loop
}

// Single-block scan: each thread owns a contiguous chunk (serial), block-scan of sums.
__global__ __launch_bounds__(1024) void k_scan(const int* __restrict__ degi,
                                               int* __restrict__ row_start,
                                               int* __restrict__ cursor, int N) {
    __shared__ int sums[1024];
    const int t = threadIdx.x;
    const int chunk = (N + 1023) / 1024;
    const int lo = t * chunk;
    const int hi = (lo + chunk < N) ? lo + chunk : N;
    int s = 0;
    for (int i = lo; i < hi; ++i) s += degi[i];
    sums[t] = s;
    __syncthreads();
    for (int off = 1; off < 1024; off <<= 1) {
        int v = (t >= off) ? sums[t - off] : 0;
        __syncthreads();
        sums[t] += v;
        __syncthreads();
    }
    int excl = sums[t] - s;
    for (int i = lo; i < hi; ++i) {
        row_start[i] = excl;
        cursor[i]    = excl;
        excl += degi[i];
    }
    if (t == 1023) row_start[N] = sums[1023];
}

__global__ void k_build(const int* __restrict__ src, const int* __restrict__ dst,
                        int* __restrict__ cursor, int* __restrict__ csr_src, int E) {
    int i = blockIdx.x * blockDim.x + threadIdx.x;
    int stride = gridDim.x * blockDim.x;
    for (int e = i; e < E; e += stride) {
        int pos = atomicAdd(&cursor[dst[e]], 1);
        csr_src[pos] = src[e];
    }
}

// ---------------- conversions ----------------
// x fp32 [Nrows][512] -> xb bf16 [Mp][512], zero-pad rows >= Nrows
__global__ void k_cvt_x(const float* __restrict__ x, unsigned short* __restrict__ xb,
                        int Nrows, int Mp) {
    int i = blockIdx.x * blockDim.x + threadIdx.x;   // one thread per 4 elements
    int total = Mp * (NFEAT / 4);
    if (i >= total) return;
    int row = i / (NFEAT / 4);
    int q   = (i % (NFEAT / 4)) * 4;
    ushort4 o;
    if (row < Nrows) {
        const float4 v = *(const float4*)&x[(size_t)row * NFEAT + q];
        o.x = f2bf(v.x); o.y = f2bf(v.y); o.z = f2bf(v.z); o.w = f2bf(v.w);
    } else {
        o.x = 0; o.y = 0; o.z = 0; o.w = 0;
    }
    *(ushort4*)&xb[(size_t)row * NFEAT + q] = o;
}

// W fp32 [K][Nc] -> Wt bf16 [Nc][K]
__global__ void k_cvt_wt(const float* __restrict__ W, unsigned short* __restrict__ Wt,
                         int K, int Nc) {
    int i = blockIdx.x * blockDim.x + threadIdx.x;
    if (i >= K * Nc) return;
    int k = i / Nc, n = i % Nc;
    Wt[(size_t)n * K + k] = f2bf(W[(size_t)k * Nc + n]);
}

// ---------------- bf16 MFMA GEMM ----------------
// C[M,N] = A[M,K] * Bt[N,K]^T. M multiple of 128 (grid.y), N = grid.x*128,
// K multiple of 32. Output bf16. m97 structure: 128x128 tile, BK=32,
// global_load_lds width-16 staging, 4 waves x 4x4 mfma_f32_16x16x32_bf16.
__global__ __launch_bounds__(256) void gemm_bf16(
    const unsigned short* __restrict__ A, const unsigned short* __restrict__ Bt,
    unsigned short* __restrict__ C, int N, int K) {
    __shared__ unsigned short As[128 * 32];
    __shared__ unsigned short Bs[128 * 32];
    const int t    = threadIdx.x;
    const int wave = t >> 6, lane = t & 63;
    const int row0 = blockIdx.y * 128, col0 = blockIdx.x * 128;
    const int wm = (wave >> 1) * 64, wn = (wave & 1) * 64;
    const int sr = lane >> 2;            // staging row within 16-row chunk
    const int sk = (lane & 3) * 8;       // staging k offset (bf16 units)
    const int quad = lane >> 4, l15 = lane & 15;

    const int ca = wave * 2;             // this wave's chunk pair
    const unsigned short* gA0 = A  + (size_t)(row0 + ca * 16 + sr) * K + sk;
    const unsigned short* gA1 = gA0 + (size_t)16 * K;
    const unsigned short* gB0 = Bt + (size_t)(col0 + ca * 16 + sr) * K + sk;
    const unsigned short* gB1 = gB0 + (size_t)16 * K;
    unsigned short* lA0 = &As[ca * 512];
    unsigned short* lA1 = &As[(ca + 1) * 512];
    unsigned short* lB0 = &Bs[ca * 512];
    unsigned short* lB1 = &Bs[(ca + 1) * 512];

    float4v acc[4][4] = {};

    for (int k0 = 0; k0 < K; k0 += 32) {
        __syncthreads();                 // prior compute done before overwrite
        load_lds16(gA0 + k0, lA0);
        load_lds16(gA1 + k0, lA1);
        load_lds16(gB0 + k0, lB0);
        load_lds16(gB1 + k0, lB1);
        __syncthreads();                 // drains vmcnt -> LDS data visible

        short8 a[4], b[4];
#pragma unroll
        for (int i = 0; i < 4; ++i) {
            a[i] = *(const short8*)&As[(wm + i * 16 + l15) * 32 + quad * 8];
            b[i] = *(const short8*)&Bs[(wn + i * 16 + l15) * 32 + quad * 8];
        }
#pragma unroll
        for (int mt = 0; mt < 4; ++mt)
#pragma unroll
            for (int nt = 0; nt < 4; ++nt)
                acc[mt][nt] = __builtin_amdgcn_mfma_f32_16x16x32_bf16(
                    a[mt], b[nt], acc[mt][nt], 0, 0, 0);
    }

    // C/D layout: col = lane&15, row = (lane>>4)*4 + reg   [m89-verified]
#pragma unroll
    for (int mt = 0; mt < 4; ++mt) {
#pragma unroll
        for (int nt = 0; nt < 4; ++nt) {
            const int c = col0 + wn + nt * 16 + l15;
#pragma unroll
            for (int r = 0; r < 4; ++r) {
                const int row = row0 + wm + mt * 16 + quad * 4 + r;
                C[(size_t)row * N + c] = f2bf(acc[mt][nt][r]);
            }
        }
    }
}

// ---------------- CSR gather aggregation (bf16 features) ----------------
template <int F, bool RELU, bool OUTF32>
__global__ __launch_bounds__(256) void k_gather(
    const int* __restrict__ row_start, const int* __restrict__ csr_src,
    const float* __restrict__ dinv, const unsigned short* __restrict__ h,
    const float* __restrict__ bias, unsigned short* __restrict__ ob,
    float* __restrict__ of, int N) {
    const int gid  = blockIdx.x * blockDim.x + threadIdx.x;
    const int node = gid >> 6;
    const int lane = gid & 63;
    if (node >= N) return;

    constexpr int EL = F / 64;           // elements per lane: 4 (F=256) or 2 (F=128)
    const float wd = dinv[node];
    const int jb = row_start[node];
    const int je = row_start[node + 1];

    float acc[EL];
    {
        const float ws = wd * wd;
        const unsigned short* hp = &h[(size_t)node * F + lane * EL];
#pragma unroll
        for (int i = 0; i < EL; ++i)
            acc[i] = fmaf(bf2f(hp[i]), ws, bias[lane * EL + i]);
    }

    for (int j = jb; j < je; ++j) {
        const int s = csr_src[j];
        const float w = dinv[s] * wd;
        const unsigned short* hp = &h[(size_t)s * F + lane * EL];
        if (EL == 4) {
            const ushort4 v = *(const ushort4*)hp;
            acc[0] = fmaf(bf2f(v.x), w, acc[0]);
            acc[1] = fmaf(bf2f(v.y), w, acc[1]);
            acc[2] = fmaf(bf2f(v.z), w, acc[2]);
            acc[3] = fmaf(bf2f(v.w), w, acc[3]);
        } else {
            const ushort2 v = *(const ushort2*)hp;
            acc[0] = fmaf(bf2f(v.x), w, acc[0]);
            acc[1] = fmaf(bf2f(v.y), w, acc[1]);
        }
    }

#pragma unroll
    for (int i = 0; i < EL; ++i) {
        float v = RELU ? fmaxf(acc[i], 0.f) : acc[i];
        if (OUTF32) of[(size_t)node * F + lane * EL + i] = v;
        else        ob[(size_t)node * F + lane * EL + i] = f2bf(v);
    }
}

extern "C" void kernel_launch(void* const* d_in, const int* in_sizes, int n_in,
                              void* d_out, int out_size, void* d_ws, size_t ws_size,
                              hipStream_t stream) {
    const float* x   = (const float*)d_in[0];
    const int*   ei  = (const int*)d_in[1];
    const float* W1  = (const float*)d_in[2];
    const float* b1  = (const float*)d_in[3];
    const float* W2  = (const float*)d_in[4];
    const float* b2  = (const float*)d_in[5];
    float*       out = (float*)d_out;

    const int N = in_sizes[0] / NFEAT;           // 50000
    const int E = in_sizes[1] / 2;               // 800000
    const int Mp = ((N + 127) / 128) * 128;      // 50048
    const int* srcp = ei;
    const int* dstp = ei + E;

    // workspace layout (256B aligned chunks)
    char* wsb = (char*)d_ws;
    auto take = [&](size_t bytes) {
        char* p = wsb;
        wsb += (bytes + 255) & ~(size_t)255;
        return p;
    };
    int*   degi      = (int*)take((size_t)N * 4);
    int*   row_start = (int*)take((size_t)(N + 1) * 4);
    int*   cursor    = (int*)take((size_t)N * 4);
    int*   csr_src   = (int*)take((size_t)E * 4);
    float* dinv      = (float*)take((size_t)N * 4);
    unsigned short* xb  = (unsigned short*)take((size_t)Mp * NFEAT * 2);  // also h2
    unsigned short* W1t = (unsigned short*)take((size_t)NH1 * NFEAT * 2);
    unsigned short* W2t = (unsigned short*)take((size_t)NH2 * NH1 * 2);
    unsigned short* h   = (unsigned short*)take((size_t)Mp * NH1 * 2);
    unsigned short* h1  = (unsigned short*)take((size_t)Mp * NH1 * 2);
    unsigned short* h2  = xb;                    // xb dead after GEMM1

    // ---- CSR build + dinv + conversions ----
    k_zero_int<<<(N + 255) / 256, 256, 0, stream>>>(degi, N);
    k_deg_int<<<1024, 256, 0, stream>>>(dstp, degi, E);
    k_dinv<<<(N + 255) / 256, 256, 0, stream>>>(degi, dinv, N);
    k_scan<<<1, 1024, 0, stream>>>(degi, row_start, cursor, N);
    k_build<<<1024, 256, 0, stream>>>(srcp, dstp, cursor, csr_src, E);
    {
        int total = Mp * (NFEAT / 4);
        k_cvt_x<<<(total + 255) / 256, 256, 0, stream>>>(x, xb, N, Mp);
    }
    k_cvt_wt<<<(NFEAT * NH1 + 255) / 256, 256, 0, stream>>>(W1, W1t, NFEAT, NH1);
    k_cvt_wt<<<(NH1 * NH2 + 255) / 256, 256, 0, stream>>>(W2, W2t, NH1, NH2);

    // ---- layer 1: h = xb@W1 (bf16) ; h1 = relu(A_hat h + b1) (bf16) ----
    {
        dim3 g(NH1 / 128, Mp / 128);
        gemm_bf16<<<g, 256, 0, stream>>>(xb, W1t, h, NH1, NFEAT);
    }
    {
        int total = N * 64;
        k_gather<NH1, true, false><<<(total + 255) / 256, 256, 0, stream>>>(
            row_start, csr_src, dinv, h, b1, h1, nullptr, N);
    }

    // ---- layer 2: h2 = h1@W2 (bf16) ; out = A_hat h2 + b2 (fp32) ----
    {
        dim3 g(NH2 / 128, Mp / 128);
        gemm_bf16<<<g, 256, 0, stream>>>(h1, W2t, h2, NH2, NH1);
    }
    {
        int total = N * 64;
        k_gather<NH2, false, true><<<(total + 255) / 256, 256, 0, stream>>>(
            row_start, csr_src, dinv, h2, b2, nullptr, out, N);
    }
}

// Round 5
// 498.703 us; speedup vs baseline: 7.5893x; 1.2208x over previous
//
#include <hip/hip_runtime.h>
#include <cstdint>
#include <cstddef>

#define NFEAT 512
#define NH1   256
#define NH2   128

typedef __attribute__((ext_vector_type(8))) short short8;
typedef __attribute__((ext_vector_type(4))) float float4v;

__device__ __forceinline__ unsigned short f2bf(float f) {
    unsigned int u = __float_as_uint(f);
    u += 0x7fffu + ((u >> 16) & 1u);   // round-to-nearest-even
    return (unsigned short)(u >> 16);
}
__device__ __forceinline__ float bf2f(unsigned short u) {
    return __uint_as_float(((unsigned int)u) << 16);
}

__device__ __forceinline__ void load_lds16(const void* g, void* l) {
    __builtin_amdgcn_global_load_lds(
        (const __attribute__((address_space(1))) void*)g,
        (__attribute__((address_space(3))) void*)l, 16, 0, 0);
}

// ---------------- CSR build ----------------
__global__ void k_zero_int(int* __restrict__ p, int n) {
    int i = blockIdx.x * blockDim.x + threadIdx.x;
    if (i < n) p[i] = 0;
}

__global__ void k_deg_int(const int* __restrict__ dst, int* __restrict__ degi, int E) {
    int i = blockIdx.x * blockDim.x + threadIdx.x;
    int stride = gridDim.x * blockDim.x;
    for (int e = i; e < E; e += stride)
        atomicAdd(&degi[dst[e]], 1);
}

__global__ void k_dinv(const int* __restrict__ degi, float* __restrict__ dinv, int n) {
    int i = blockIdx.x * blockDim.x + threadIdx.x;
    if (i < n) dinv[i] = rsqrtf((float)(degi[i] + 1));   // +1 = self-loop
}

// Single-block scan: each thread owns a contiguous chunk (serial), block-scan of sums.
__global__ __launch_bounds__(1024) void k_scan(const int* __restrict__ degi,
                                               int* __restrict__ row_start,
                                               int* __restrict__ cursor, int N) {
    __shared__ int sums[1024];
    const int t = threadIdx.x;
    const int chunk = (N + 1023) / 1024;
    const int lo = t * chunk;
    const int hi = (lo + chunk < N) ? lo + chunk : N;
    int s = 0;
    for (int i = lo; i < hi; ++i) s += degi[i];
    sums[t] = s;
    __syncthreads();
    for (int off = 1; off < 1024; off <<= 1) {
        int v = (t >= off) ? sums[t - off] : 0;
        __syncthreads();
        sums[t] += v;
        __syncthreads();
    }
    int excl = sums[t] - s;
    for (int i = lo; i < hi; ++i) {
        row_start[i] = excl;
        cursor[i]    = excl;
        excl += degi[i];
    }
    if (t == 1023) row_start[N] = sums[1023];
}

__global__ void k_build(const int* __restrict__ src, const int* __restrict__ dst,
                        int* __restrict__ cursor, int* __restrict__ csr_src, int E) {
    int i = blockIdx.x * blockDim.x + threadIdx.x;
    int stride = gridDim.x * blockDim.x;
    for (int e = i; e < E; e += stride) {
        int pos = atomicAdd(&cursor[dst[e]], 1);
        csr_src[pos] = src[e];
    }
}

// ---------------- conversions ----------------
// x fp32 [Nrows][512] -> xb bf16 [Mp][512] with row pre-scale by dinv[row];
// zero-pad rows >= Nrows. (D^{-1/2} X) W == D^{-1/2} (X W): scaling commutes.
__global__ void k_cvt_x(const float* __restrict__ x, const float* __restrict__ dinv,
                        unsigned short* __restrict__ xb, int Nrows, int Mp) {
    int i = blockIdx.x * blockDim.x + threadIdx.x;   // one thread per 4 elements
    int total = Mp * (NFEAT / 4);
    if (i >= total) return;
    int row = i / (NFEAT / 4);
    int q   = (i % (NFEAT / 4)) * 4;
    ushort4 o;
    if (row < Nrows) {
        const float w = dinv[row];
        const float4 v = *(const float4*)&x[(size_t)row * NFEAT + q];
        o.x = f2bf(v.x * w); o.y = f2bf(v.y * w);
        o.z = f2bf(v.z * w); o.w = f2bf(v.w * w);
    } else {
        o.x = 0; o.y = 0; o.z = 0; o.w = 0;
    }
    *(ushort4*)&xb[(size_t)row * NFEAT + q] = o;
}

// W fp32 [K][Nc] -> Wt bf16 [Nc][K]
__global__ void k_cvt_wt(const float* __restrict__ W, unsigned short* __restrict__ Wt,
                         int K, int Nc) {
    int i = blockIdx.x * blockDim.x + threadIdx.x;
    if (i >= K * Nc) return;
    int k = i / Nc, n = i % Nc;
    Wt[(size_t)n * K + k] = f2bf(W[(size_t)k * Nc + n]);
}

// ---------------- bf16 MFMA GEMM ----------------
// C[M,N] = A[M,K] * Bt[N,K]^T. m97 structure: 128x128 tile, BK=32,
// global_load_lds width-16 staging, 4 waves x 4x4 mfma_f32_16x16x32_bf16.
__global__ __launch_bounds__(256) void gemm_bf16(
    const unsigned short* __restrict__ A, const unsigned short* __restrict__ Bt,
    unsigned short* __restrict__ C, int N, int K) {
    __shared__ unsigned short As[128 * 32];
    __shared__ unsigned short Bs[128 * 32];
    const int t    = threadIdx.x;
    const int wave = t >> 6, lane = t & 63;
    const int row0 = blockIdx.y * 128, col0 = blockIdx.x * 128;
    const int wm = (wave >> 1) * 64, wn = (wave & 1) * 64;
    const int sr = lane >> 2;            // staging row within 16-row chunk
    const int sk = (lane & 3) * 8;       // staging k offset (bf16 units)
    const int quad = lane >> 4, l15 = lane & 15;

    const int ca = wave * 2;             // this wave's chunk pair
    const unsigned short* gA0 = A  + (size_t)(row0 + ca * 16 + sr) * K + sk;
    const unsigned short* gA1 = gA0 + (size_t)16 * K;
    const unsigned short* gB0 = Bt + (size_t)(col0 + ca * 16 + sr) * K + sk;
    const unsigned short* gB1 = gB0 + (size_t)16 * K;
    unsigned short* lA0 = &As[ca * 512];
    unsigned short* lA1 = &As[(ca + 1) * 512];
    unsigned short* lB0 = &Bs[ca * 512];
    unsigned short* lB1 = &Bs[(ca + 1) * 512];

    float4v acc[4][4] = {};

    for (int k0 = 0; k0 < K; k0 += 32) {
        __syncthreads();
        load_lds16(gA0 + k0, lA0);
        load_lds16(gA1 + k0, lA1);
        load_lds16(gB0 + k0, lB0);
        load_lds16(gB1 + k0, lB1);
        __syncthreads();

        short8 a[4], b[4];
#pragma unroll
        for (int i = 0; i < 4; ++i) {
            a[i] = *(const short8*)&As[(wm + i * 16 + l15) * 32 + quad * 8];
            b[i] = *(const short8*)&Bs[(wn + i * 16 + l15) * 32 + quad * 8];
        }
#pragma unroll
        for (int mt = 0; mt < 4; ++mt)
#pragma unroll
            for (int nt = 0; nt < 4; ++nt)
                acc[mt][nt] = __builtin_amdgcn_mfma_f32_16x16x32_bf16(
                    a[mt], b[nt], acc[mt][nt], 0, 0, 0);
    }

    // C/D layout: col = lane&15, row = (lane>>4)*4 + reg   [m89-verified]
#pragma unroll
    for (int mt = 0; mt < 4; ++mt) {
#pragma unroll
        for (int nt = 0; nt < 4; ++nt) {
            const int c = col0 + wn + nt * 16 + l15;
#pragma unroll
            for (int r = 0; r < 4; ++r) {
                const int row = row0 + wm + mt * 16 + quad * 4 + r;
                C[(size_t)row * N + c] = f2bf(acc[mt][nt][r]);
            }
        }
    }
}

// ---------------- CSR gather aggregation (bf16 features, pre-scaled rows) ----
// h rows are already scaled by dinv[src]. Per node d:
//   acc = h[d] + sum_{s in N(d)} h[s]          (pure adds, no per-edge weights)
//   val = acc * dinv[d] + bias
//   RELU layer: store bf16( relu(val) * dinv[d] )   (pre-scale for next layer)
//   final layer: store fp32( val )
template <int F, bool RELU, bool OUTF32>
__global__ __launch_bounds__(256) void k_gather(
    const int* __restrict__ row_start, const int* __restrict__ csr_src,
    const float* __restrict__ dinv, const unsigned short* __restrict__ h,
    const float* __restrict__ bias, unsigned short* __restrict__ ob,
    float* __restrict__ of, int N) {
    const int gid  = blockIdx.x * blockDim.x + threadIdx.x;
    const int node = gid >> 6;
    const int lane = gid & 63;
    if (node >= N) return;

    constexpr int EL = F / 64;           // 4 (F=256) or 2 (F=128)
    const float wd = dinv[node];
    const int jb = row_start[node];
    const int je = row_start[node + 1];
    const unsigned short* hl = h + (size_t)lane * EL;

    float acc[EL];
    {   // self-loop term (h already dinv-scaled)
        const unsigned short* hp = hl + (size_t)node * F;
        if (EL == 4) {
            const ushort4 v = *(const ushort4*)hp;
            acc[0] = bf2f(v.x); acc[1] = bf2f(v.y);
            acc[2] = bf2f(v.z); acc[3] = bf2f(v.w);
        } else {
            const ushort2 v = *(const ushort2*)hp;
            acc[0] = bf2f(v.x); acc[1] = bf2f(v.y);
        }
    }

    for (int j0 = jb; j0 < je; j0 += 64) {
        // one coalesced index load per 64 edges, broadcast via shfl
        int jj = j0 + lane;
        if (jj >= je) jj = je - 1;
        const int myi = csr_src[jj];
        const int rem = je - j0;
        const int cnt = rem < 64 ? rem : 64;
        int i = 0;
        for (; i + 4 <= cnt; i += 4) {   // 4 independent row loads in flight
            const int s0 = __shfl(myi, i + 0);
            const int s1 = __shfl(myi, i + 1);
            const int s2 = __shfl(myi, i + 2);
            const int s3 = __shfl(myi, i + 3);
            if (EL == 4) {
                const ushort4 v0 = *(const ushort4*)(hl + (size_t)s0 * F);
                const ushort4 v1 = *(const ushort4*)(hl + (size_t)s1 * F);
                const ushort4 v2 = *(const ushort4*)(hl + (size_t)s2 * F);
                const ushort4 v3 = *(const ushort4*)(hl + (size_t)s3 * F);
                acc[0] += bf2f(v0.x) + bf2f(v1.x) + bf2f(v2.x) + bf2f(v3.x);
                acc[1] += bf2f(v0.y) + bf2f(v1.y) + bf2f(v2.y) + bf2f(v3.y);
                acc[2] += bf2f(v0.z) + bf2f(v1.z) + bf2f(v2.z) + bf2f(v3.z);
                acc[3] += bf2f(v0.w) + bf2f(v1.w) + bf2f(v2.w) + bf2f(v3.w);
            } else {
                const ushort2 v0 = *(const ushort2*)(hl + (size_t)s0 * F);
                const ushort2 v1 = *(const ushort2*)(hl + (size_t)s1 * F);
                const ushort2 v2 = *(const ushort2*)(hl + (size_t)s2 * F);
                const ushort2 v3 = *(const ushort2*)(hl + (size_t)s3 * F);
                acc[0] += bf2f(v0.x) + bf2f(v1.x) + bf2f(v2.x) + bf2f(v3.x);
                acc[1] += bf2f(v0.y) + bf2f(v1.y) + bf2f(v2.y) + bf2f(v3.y);
            }
        }
        for (; i < cnt; ++i) {
            const int s = __shfl(myi, i);
            const unsigned short* hp = hl + (size_t)s * F;
            if (EL == 4) {
                const ushort4 v = *(const ushort4*)hp;
                acc[0] += bf2f(v.x); acc[1] += bf2f(v.y);
                acc[2] += bf2f(v.z); acc[3] += bf2f(v.w);
            } else {
                const ushort2 v = *(const ushort2*)hp;
                acc[0] += bf2f(v.x); acc[1] += bf2f(v.y);
            }
        }
    }

#pragma unroll
    for (int i = 0; i < EL; ++i) {
        float v = fmaf(acc[i], wd, bias[lane * EL + i]);
        if (OUTF32) {
            of[(size_t)node * F + lane * EL + i] = v;
        } else {
            if (RELU) v = fmaxf(v, 0.f);
            ob[(size_t)node * F + lane * EL + i] = f2bf(v * wd);  // pre-scale for next layer
        }
    }
}

extern "C" void kernel_launch(void* const* d_in, const int* in_sizes, int n_in,
                              void* d_out, int out_size, void* d_ws, size_t ws_size,
                              hipStream_t stream) {
    const float* x   = (const float*)d_in[0];
    const int*   ei  = (const int*)d_in[1];
    const float* W1  = (const float*)d_in[2];
    const float* b1  = (const float*)d_in[3];
    const float* W2  = (const float*)d_in[4];
    const float* b2  = (const float*)d_in[5];
    float*       out = (float*)d_out;

    const int N = in_sizes[0] / NFEAT;           // 50000
    const int E = in_sizes[1] / 2;               // 800000
    const int Mp = ((N + 127) / 128) * 128;      // 50048
    const int* srcp = ei;
    const int* dstp = ei + E;

    // workspace layout (256B aligned chunks)
    char* wsb = (char*)d_ws;
    auto take = [&](size_t bytes) {
        char* p = wsb;
        wsb += (bytes + 255) & ~(size_t)255;
        return p;
    };
    int*   degi      = (int*)take((size_t)N * 4);
    int*   row_start = (int*)take((size_t)(N + 1) * 4);
    int*   cursor    = (int*)take((size_t)N * 4);
    int*   csr_src   = (int*)take((size_t)E * 4);
    float* dinv      = (float*)take((size_t)N * 4);
    unsigned short* xb  = (unsigned short*)take((size_t)Mp * NFEAT * 2);  // also h2
    unsigned short* W1t = (unsigned short*)take((size_t)NH1 * NFEAT * 2);
    unsigned short* W2t = (unsigned short*)take((size_t)NH2 * NH1 * 2);
    unsigned short* h   = (unsigned short*)take((size_t)Mp * NH1 * 2);
    unsigned short* h1  = (unsigned short*)take((size_t)Mp * NH1 * 2);
    unsigned short* h2  = xb;                    // xb dead after GEMM1

    // ---- CSR build + dinv + conversions ----
    k_zero_int<<<(N + 255) / 256, 256, 0, stream>>>(degi, N);
    k_deg_int<<<1024, 256, 0, stream>>>(dstp, degi, E);
    k_dinv<<<(N + 255) / 256, 256, 0, stream>>>(degi, dinv, N);
    k_scan<<<1, 1024, 0, stream>>>(degi, row_start, cursor, N);
    k_build<<<1024, 256, 0, stream>>>(srcp, dstp, cursor, csr_src, E);
    {
        int total = Mp * (NFEAT / 4);
        k_cvt_x<<<(total + 255) / 256, 256, 0, stream>>>(x, dinv, xb, N, Mp);
    }
    k_cvt_wt<<<(NFEAT * NH1 + 255) / 256, 256, 0, stream>>>(W1, W1t, NFEAT, NH1);
    k_cvt_wt<<<(NH1 * NH2 + 255) / 256, 256, 0, stream>>>(W2, W2t, NH1, NH2);

    // ---- layer 1: h = (x*dinv)@W1 (bf16) ; h1 = relu(...)*dinv (bf16) ----
    {
        dim3 g(NH1 / 128, Mp / 128);
        gemm_bf16<<<g, 256, 0, stream>>>(xb, W1t, h, NH1, NFEAT);
    }
    {
        int total = N * 64;
        k_gather<NH1, true, false><<<(total + 255) / 256, 256, 0, stream>>>(
            row_start, csr_src, dinv, h, b1, h1, nullptr, N);
    }

    // ---- layer 2: h2 = h1s@W2 (bf16) ; out = gather + b2 (fp32) ----
    {
        dim3 g(NH2 / 128, Mp / 128);
        gemm_bf16<<<g, 256, 0, stream>>>(h1, W2t, h2, NH2, NH1);
    }
    {
        int total = N * 64;
        k_gather<NH2, false, true><<<(total + 255) / 256, 256, 0, stream>>>(
            row_start, csr_src, dinv, h2, b2, nullptr, out, N);
    }
}

// Round 6
// 415.516 us; speedup vs baseline: 9.1087x; 1.2002x over previous
//
#include <hip/hip_runtime.h>
#include <cstdint>
#include <cstddef>

#define NFEAT 512
#define NH1   256
#define NH2   128

#define SCAN_BLOCK 256
#define SCAN_ELEMS 4
#define SCAN_TILE  (SCAN_BLOCK * SCAN_ELEMS)   // 1024

typedef __attribute__((ext_vector_type(8))) short short8;
typedef __attribute__((ext_vector_type(4))) float float4v;

__device__ __forceinline__ unsigned short f2bf(float f) {
    unsigned int u = __float_as_uint(f);
    u += 0x7fffu + ((u >> 16) & 1u);   // round-to-nearest-even
    return (unsigned short)(u >> 16);
}
__device__ __forceinline__ float bf2f(unsigned short u) {
    return __uint_as_float(((unsigned int)u) << 16);
}

__device__ __forceinline__ void load_lds16(const void* g, void* l) {
    __builtin_amdgcn_global_load_lds(
        (const __attribute__((address_space(1))) void*)g,
        (__attribute__((address_space(3))) void*)l, 16, 0, 0);
}

// ---------------- CSR build ----------------
__global__ void k_zero_int(int* __restrict__ p, int n) {
    int i = blockIdx.x * blockDim.x + threadIdx.x;
    if (i < n) p[i] = 0;
}

__global__ void k_deg_int(const int* __restrict__ dst, int* __restrict__ degi, int E) {
    int i = blockIdx.x * blockDim.x + threadIdx.x;
    int stride = gridDim.x * blockDim.x;
    for (int e = i; e < E; e += stride)
        atomicAdd(&degi[dst[e]], 1);
}

__global__ void k_dinv(const int* __restrict__ degi, float* __restrict__ dinv, int n) {
    int i = blockIdx.x * blockDim.x + threadIdx.x;
    if (i < n) dinv[i] = rsqrtf((float)(degi[i] + 1));   // +1 = self-loop
}

// ---- three-phase exclusive scan over degi[0..N) ----
// Phase 1: per-block (1024-element tile) sums.
__global__ __launch_bounds__(SCAN_BLOCK) void k_scan1(
    const int* __restrict__ degi, int* __restrict__ blocksums, int N) {
    __shared__ int red[SCAN_BLOCK];
    const int t = threadIdx.x;
    const int base = blockIdx.x * SCAN_TILE + t * SCAN_ELEMS;
    int s = 0;
#pragma unroll
    for (int i = 0; i < SCAN_ELEMS; ++i) {
        const int idx = base + i;
        if (idx < N) s += degi[idx];
    }
    red[t] = s;
    __syncthreads();
    for (int off = SCAN_BLOCK / 2; off > 0; off >>= 1) {
        if (t < off) red[t] += red[t + off];
        __syncthreads();
    }
    if (t == 0) blocksums[blockIdx.x] = red[0];
}

// Phase 2: single block scans blocksums (nb <= 1024), writes exclusive block
// offsets and row_start[N] = total.
__global__ __launch_bounds__(1024) void k_scan2(
    const int* __restrict__ blocksums, int* __restrict__ blockoffs,
    int* __restrict__ row_start, int nb, int N) {
    __shared__ int sm[1024];
    const int t = threadIdx.x;
    const int v = (t < nb) ? blocksums[t] : 0;
    sm[t] = v;
    __syncthreads();
    for (int off = 1; off < 1024; off <<= 1) {
        const int x = (t >= off) ? sm[t - off] : 0;
        __syncthreads();
        sm[t] += x;
        __syncthreads();
    }
    if (t < nb) blockoffs[t] = sm[t] - v;
    if (t == 1023) row_start[N] = sm[1023];
}

// Phase 3: block-level exclusive scan + block offset -> row_start / cursor.
__global__ __launch_bounds__(SCAN_BLOCK) void k_scan3(
    const int* __restrict__ degi, const int* __restrict__ blockoffs,
    int* __restrict__ row_start, int* __restrict__ cursor, int N) {
    __shared__ int tsum[SCAN_BLOCK];
    const int t = threadIdx.x;
    const int base = blockIdx.x * SCAN_TILE + t * SCAN_ELEMS;
    int v[SCAN_ELEMS];
    int s = 0;
#pragma unroll
    for (int i = 0; i < SCAN_ELEMS; ++i) {
        const int idx = base + i;
        v[i] = (idx < N) ? degi[idx] : 0;
        s += v[i];
    }
    tsum[t] = s;
    __syncthreads();
    for (int off = 1; off < SCAN_BLOCK; off <<= 1) {
        const int x = (t >= off) ? tsum[t - off] : 0;
        __syncthreads();
        tsum[t] += x;
        __syncthreads();
    }
    int excl = blockoffs[blockIdx.x] + tsum[t] - s;
#pragma unroll
    for (int i = 0; i < SCAN_ELEMS; ++i) {
        const int idx = base + i;
        if (idx < N) {
            row_start[idx] = excl;
            cursor[idx]    = excl;
        }
        excl += v[i];
    }
}

__global__ void k_build(const int* __restrict__ src, const int* __restrict__ dst,
                        int* __restrict__ cursor, int* __restrict__ csr_src, int E) {
    int i = blockIdx.x * blockDim.x + threadIdx.x;
    int stride = gridDim.x * blockDim.x;
    for (int e = i; e < E; e += stride) {
        int pos = atomicAdd(&cursor[dst[e]], 1);
        csr_src[pos] = src[e];
    }
}

// ---------------- conversions ----------------
// x fp32 [Nrows][512] -> xb bf16 [Mp][512] with row pre-scale by dinv[row];
// zero-pad rows >= Nrows. (D^{-1/2} X) W == D^{-1/2} (X W): scaling commutes.
__global__ void k_cvt_x(const float* __restrict__ x, const float* __restrict__ dinv,
                        unsigned short* __restrict__ xb, int Nrows, int Mp) {
    int i = blockIdx.x * blockDim.x + threadIdx.x;   // one thread per 4 elements
    int total = Mp * (NFEAT / 4);
    if (i >= total) return;
    int row = i / (NFEAT / 4);
    int q   = (i % (NFEAT / 4)) * 4;
    ushort4 o;
    if (row < Nrows) {
        const float w = dinv[row];
        const float4 v = *(const float4*)&x[(size_t)row * NFEAT + q];
        o.x = f2bf(v.x * w); o.y = f2bf(v.y * w);
        o.z = f2bf(v.z * w); o.w = f2bf(v.w * w);
    } else {
        o.x = 0; o.y = 0; o.z = 0; o.w = 0;
    }
    *(ushort4*)&xb[(size_t)row * NFEAT + q] = o;
}

// W fp32 [K][Nc] -> Wt bf16 [Nc][K]
__global__ void k_cvt_wt(const float* __restrict__ W, unsigned short* __restrict__ Wt,
                         int K, int Nc) {
    int i = blockIdx.x * blockDim.x + threadIdx.x;
    if (i >= K * Nc) return;
    int k = i / Nc, n = i % Nc;
    Wt[(size_t)n * K + k] = f2bf(W[(size_t)k * Nc + n]);
}

// ---------------- bf16 MFMA GEMM ----------------
// C[M,N] = A[M,K] * Bt[N,K]^T. m97 structure: 128x128 tile, BK=32,
// global_load_lds width-16 staging, 4 waves x 4x4 mfma_f32_16x16x32_bf16.
__global__ __launch_bounds__(256) void gemm_bf16(
    const unsigned short* __restrict__ A, const unsigned short* __restrict__ Bt,
    unsigned short* __restrict__ C, int N, int K) {
    __shared__ unsigned short As[128 * 32];
    __shared__ unsigned short Bs[128 * 32];
    const int t    = threadIdx.x;
    const int wave = t >> 6, lane = t & 63;
    const int row0 = blockIdx.y * 128, col0 = blockIdx.x * 128;
    const int wm = (wave >> 1) * 64, wn = (wave & 1) * 64;
    const int sr = lane >> 2;            // staging row within 16-row chunk
    const int sk = (lane & 3) * 8;       // staging k offset (bf16 units)
    const int quad = lane >> 4, l15 = lane & 15;

    const int ca = wave * 2;             // this wave's chunk pair
    const unsigned short* gA0 = A  + (size_t)(row0 + ca * 16 + sr) * K + sk;
    const unsigned short* gA1 = gA0 + (size_t)16 * K;
    const unsigned short* gB0 = Bt + (size_t)(col0 + ca * 16 + sr) * K + sk;
    const unsigned short* gB1 = gB0 + (size_t)16 * K;
    unsigned short* lA0 = &As[ca * 512];
    unsigned short* lA1 = &As[(ca + 1) * 512];
    unsigned short* lB0 = &Bs[ca * 512];
    unsigned short* lB1 = &Bs[(ca + 1) * 512];

    float4v acc[4][4] = {};

    for (int k0 = 0; k0 < K; k0 += 32) {
        __syncthreads();
        load_lds16(gA0 + k0, lA0);
        load_lds16(gA1 + k0, lA1);
        load_lds16(gB0 + k0, lB0);
        load_lds16(gB1 + k0, lB1);
        __syncthreads();

        short8 a[4], b[4];
#pragma unroll
        for (int i = 0; i < 4; ++i) {
            a[i] = *(const short8*)&As[(wm + i * 16 + l15) * 32 + quad * 8];
            b[i] = *(const short8*)&Bs[(wn + i * 16 + l15) * 32 + quad * 8];
        }
#pragma unroll
        for (int mt = 0; mt < 4; ++mt)
#pragma unroll
            for (int nt = 0; nt < 4; ++nt)
                acc[mt][nt] = __builtin_amdgcn_mfma_f32_16x16x32_bf16(
                    a[mt], b[nt], acc[mt][nt], 0, 0, 0);
    }

    // C/D layout: col = lane&15, row = (lane>>4)*4 + reg   [m89-verified]
#pragma unroll
    for (int mt = 0; mt < 4; ++mt) {
#pragma unroll
        for (int nt = 0; nt < 4; ++nt) {
            const int c = col0 + wn + nt * 16 + l15;
#pragma unroll
            for (int r = 0; r < 4; ++r) {
                const int row = row0 + wm + mt * 16 + quad * 4 + r;
                C[(size_t)row * N + c] = f2bf(acc[mt][nt][r]);
            }
        }
    }
}

// ---------------- CSR gather aggregation (bf16 features, pre-scaled rows) ----
// h rows are already scaled by dinv[src]. Per node d:
//   acc = h[d] + sum_{s in N(d)} h[s]          (pure adds, no per-edge weights)
//   val = acc * dinv[d] + bias
//   RELU layer: store bf16( relu(val) * dinv[d] )   (pre-scale for next layer)
//   final layer: store fp32( val )
template <int F, bool RELU, bool OUTF32>
__global__ __launch_bounds__(256) void k_gather(
    const int* __restrict__ row_start, const int* __restrict__ csr_src,
    const float* __restrict__ dinv, const unsigned short* __restrict__ h,
    const float* __restrict__ bias, unsigned short* __restrict__ ob,
    float* __restrict__ of, int N) {
    const int gid  = blockIdx.x * blockDim.x + threadIdx.x;
    const int node = gid >> 6;
    const int lane = gid & 63;
    if (node >= N) return;

    constexpr int EL = F / 64;           // 4 (F=256) or 2 (F=128)
    const float wd = dinv[node];
    const int jb = row_start[node];
    const int je = row_start[node + 1];
    const unsigned short* hl = h + (size_t)lane * EL;

    float acc[EL];
    {   // self-loop term (h already dinv-scaled)
        const unsigned short* hp = hl + (size_t)node * F;
        if (EL == 4) {
            const ushort4 v = *(const ushort4*)hp;
            acc[0] = bf2f(v.x); acc[1] = bf2f(v.y);
            acc[2] = bf2f(v.z); acc[3] = bf2f(v.w);
        } else {
            const ushort2 v = *(const ushort2*)hp;
            acc[0] = bf2f(v.x); acc[1] = bf2f(v.y);
        }
    }

    for (int j0 = jb; j0 < je; j0 += 64) {
        // one coalesced index load per 64 edges, broadcast via shfl
        int jj = j0 + lane;
        if (jj >= je) jj = je - 1;
        const int myi = csr_src[jj];
        const int rem = je - j0;
        const int cnt = rem < 64 ? rem : 64;
        int i = 0;
        for (; i + 4 <= cnt; i += 4) {   // 4 independent row loads in flight
            const int s0 = __shfl(myi, i + 0);
            const int s1 = __shfl(myi, i + 1);
            const int s2 = __shfl(myi, i + 2);
            const int s3 = __shfl(myi, i + 3);
            if (EL == 4) {
                const ushort4 v0 = *(const ushort4*)(hl + (size_t)s0 * F);
                const ushort4 v1 = *(const ushort4*)(hl + (size_t)s1 * F);
                const ushort4 v2 = *(const ushort4*)(hl + (size_t)s2 * F);
                const ushort4 v3 = *(const ushort4*)(hl + (size_t)s3 * F);
                acc[0] += bf2f(v0.x) + bf2f(v1.x) + bf2f(v2.x) + bf2f(v3.x);
                acc[1] += bf2f(v0.y) + bf2f(v1.y) + bf2f(v2.y) + bf2f(v3.y);
                acc[2] += bf2f(v0.z) + bf2f(v1.z) + bf2f(v2.z) + bf2f(v3.z);
                acc[3] += bf2f(v0.w) + bf2f(v1.w) + bf2f(v2.w) + bf2f(v3.w);
            } else {
                const ushort2 v0 = *(const ushort2*)(hl + (size_t)s0 * F);
                const ushort2 v1 = *(const ushort2*)(hl + (size_t)s1 * F);
                const ushort2 v2 = *(const ushort2*)(hl + (size_t)s2 * F);
                const ushort2 v3 = *(const ushort2*)(hl + (size_t)s3 * F);
                acc[0] += bf2f(v0.x) + bf2f(v1.x) + bf2f(v2.x) + bf2f(v3.x);
                acc[1] += bf2f(v0.y) + bf2f(v1.y) + bf2f(v2.y) + bf2f(v3.y);
            }
        }
        for (; i < cnt; ++i) {
            const int s = __shfl(myi, i);
            const unsigned short* hp = hl + (size_t)s * F;
            if (EL == 4) {
                const ushort4 v = *(const ushort4*)hp;
                acc[0] += bf2f(v.x); acc[1] += bf2f(v.y);
                acc[2] += bf2f(v.z); acc[3] += bf2f(v.w);
            } else {
                const ushort2 v = *(const ushort2*)hp;
                acc[0] += bf2f(v.x); acc[1] += bf2f(v.y);
            }
        }
    }

#pragma unroll
    for (int i = 0; i < EL; ++i) {
        float v = fmaf(acc[i], wd, bias[lane * EL + i]);
        if (OUTF32) {
            of[(size_t)node * F + lane * EL + i] = v;
        } else {
            if (RELU) v = fmaxf(v, 0.f);
            ob[(size_t)node * F + lane * EL + i] = f2bf(v * wd);  // pre-scale for next layer
        }
    }
}

extern "C" void kernel_launch(void* const* d_in, const int* in_sizes, int n_in,
                              void* d_out, int out_size, void* d_ws, size_t ws_size,
                              hipStream_t stream) {
    const float* x   = (const float*)d_in[0];
    const int*   ei  = (const int*)d_in[1];
    const float* W1  = (const float*)d_in[2];
    const float* b1  = (const float*)d_in[3];
    const float* W2  = (const float*)d_in[4];
    const float* b2  = (const float*)d_in[5];
    float*       out = (float*)d_out;

    const int N = in_sizes[0] / NFEAT;           // 50000
    const int E = in_sizes[1] / 2;               // 800000
    const int Mp = ((N + 127) / 128) * 128;      // 50048
    const int* srcp = ei;
    const int* dstp = ei + E;
    const int nScanBlocks = (N + SCAN_TILE - 1) / SCAN_TILE;   // 49

    // workspace layout (256B aligned chunks)
    char* wsb = (char*)d_ws;
    auto take = [&](size_t bytes) {
        char* p = wsb;
        wsb += (bytes + 255) & ~(size_t)255;
        return p;
    };
    int*   degi      = (int*)take((size_t)N * 4);
    int*   row_start = (int*)take((size_t)(N + 1) * 4);
    int*   cursor    = (int*)take((size_t)N * 4);
    int*   csr_src   = (int*)take((size_t)E * 4);
    int*   blocksums = (int*)take((size_t)1024 * 4);
    int*   blockoffs = (int*)take((size_t)1024 * 4);
    float* dinv      = (float*)take((size_t)N * 4);
    unsigned short* xb  = (unsigned short*)take((size_t)Mp * NFEAT * 2);  // also h2
    unsigned short* W1t = (unsigned short*)take((size_t)NH1 * NFEAT * 2);
    unsigned short* W2t = (unsigned short*)take((size_t)NH2 * NH1 * 2);
    unsigned short* h   = (unsigned short*)take((size_t)Mp * NH1 * 2);
    unsigned short* h1  = (unsigned short*)take((size_t)Mp * NH1 * 2);
    unsigned short* h2  = xb;                    // xb dead after GEMM1

    // ---- CSR build + dinv + conversions ----
    k_zero_int<<<(N + 255) / 256, 256, 0, stream>>>(degi, N);
    k_deg_int<<<1024, 256, 0, stream>>>(dstp, degi, E);
    k_dinv<<<(N + 255) / 256, 256, 0, stream>>>(degi, dinv, N);
    k_scan1<<<nScanBlocks, SCAN_BLOCK, 0, stream>>>(degi, blocksums, N);
    k_scan2<<<1, 1024, 0, stream>>>(blocksums, blockoffs, row_start, nScanBlocks, N);
    k_scan3<<<nScanBlocks, SCAN_BLOCK, 0, stream>>>(degi, blockoffs, row_start, cursor, N);
    k_build<<<1024, 256, 0, stream>>>(srcp, dstp, cursor, csr_src, E);
    {
        int total = Mp * (NFEAT / 4);
        k_cvt_x<<<(total + 255) / 256, 256, 0, stream>>>(x, dinv, xb, N, Mp);
    }
    k_cvt_wt<<<(NFEAT * NH1 + 255) / 256, 256, 0, stream>>>(W1, W1t, NFEAT, NH1);
    k_cvt_wt<<<(NH1 * NH2 + 255) / 256, 256, 0, stream>>>(W2, W2t, NH1, NH2);

    // ---- layer 1: h = (x*dinv)@W1 (bf16) ; h1 = relu(...)*dinv (bf16) ----
    {
        dim3 g(NH1 / 128, Mp / 128);
        gemm_bf16<<<g, 256, 0, stream>>>(xb, W1t, h, NH1, NFEAT);
    }
    {
        int total = N * 64;
        k_gather<NH1, true, false><<<(total + 255) / 256, 256, 0, stream>>>(
            row_start, csr_src, dinv, h, b1, h1, nullptr, N);
    }

    // ---- layer 2: h2 = h1s@W2 (bf16) ; out = gather + b2 (fp32) ----
    {
        dim3 g(NH2 / 128, Mp / 128);
        gemm_bf16<<<g, 256, 0, stream>>>(h1, W2t, h2, NH2, NH1);
    }
    {
        int total = N * 64;
        k_gather<NH2, false, true><<<(total + 255) / 256, 256, 0, stream>>>(
            row_start, csr_src, dinv, h2, b2, nullptr, out, N);
    }
}

// Round 7
// 406.150 us; speedup vs baseline: 9.3187x; 1.0231x over previous
//
#include <hip/hip_runtime.h>
#include <cstdint>
#include <cstddef>

#define NFEAT 512
#define NH1   256
#define NH2   128

#define SCAN_BLOCK 256
#define SCAN_ELEMS 4
#define SCAN_TILE  (SCAN_BLOCK * SCAN_ELEMS)   // 1024

typedef __attribute__((ext_vector_type(8))) short short8;
typedef __attribute__((ext_vector_type(4))) float float4v;

__device__ __forceinline__ unsigned short f2bf(float f) {
    unsigned int u = __float_as_uint(f);
    u += 0x7fffu + ((u >> 16) & 1u);   // round-to-nearest-even
    return (unsigned short)(u >> 16);
}
__device__ __forceinline__ float bf2f(unsigned short u) {
    return __uint_as_float(((unsigned int)u) << 16);
}

__device__ __forceinline__ void load_lds16(const void* g, void* l) {
    __builtin_amdgcn_global_load_lds(
        (const __attribute__((address_space(1))) void*)g,
        (__attribute__((address_space(3))) void*)l, 16, 0, 0);
}

// ---------------- CSR build ----------------
__global__ void k_zero_int(int* __restrict__ p, int n) {
    int i = blockIdx.x * blockDim.x + threadIdx.x;
    if (i < n) p[i] = 0;
}

__global__ void k_deg_int(const int* __restrict__ dst, int* __restrict__ degi, int E) {
    int i = blockIdx.x * blockDim.x + threadIdx.x;
    int stride = gridDim.x * blockDim.x;
    for (int e = i; e < E; e += stride)
        atomicAdd(&degi[dst[e]], 1);
}

__global__ void k_dinv(const int* __restrict__ degi, float* __restrict__ dinv, int n) {
    int i = blockIdx.x * blockDim.x + threadIdx.x;
    if (i < n) dinv[i] = rsqrtf((float)(degi[i] + 1));   // +1 = self-loop
}

// ---- three-phase exclusive scan over degi[0..N) ----
__global__ __launch_bounds__(SCAN_BLOCK) void k_scan1(
    const int* __restrict__ degi, int* __restrict__ blocksums, int N) {
    __shared__ int red[SCAN_BLOCK];
    const int t = threadIdx.x;
    const int base = blockIdx.x * SCAN_TILE + t * SCAN_ELEMS;
    int s = 0;
#pragma unroll
    for (int i = 0; i < SCAN_ELEMS; ++i) {
        const int idx = base + i;
        if (idx < N) s += degi[idx];
    }
    red[t] = s;
    __syncthreads();
    for (int off = SCAN_BLOCK / 2; off > 0; off >>= 1) {
        if (t < off) red[t] += red[t + off];
        __syncthreads();
    }
    if (t == 0) blocksums[blockIdx.x] = red[0];
}

__global__ __launch_bounds__(1024) void k_scan2(
    const int* __restrict__ blocksums, int* __restrict__ blockoffs,
    int* __restrict__ row_start, int nb, int N) {
    __shared__ int sm[1024];
    const int t = threadIdx.x;
    const int v = (t < nb) ? blocksums[t] : 0;
    sm[t] = v;
    __syncthreads();
    for (int off = 1; off < 1024; off <<= 1) {
        const int x = (t >= off) ? sm[t - off] : 0;
        __syncthreads();
        sm[t] += x;
        __syncthreads();
    }
    if (t < nb) blockoffs[t] = sm[t] - v;
    if (t == 1023) row_start[N] = sm[1023];
}

__global__ __launch_bounds__(SCAN_BLOCK) void k_scan3(
    const int* __restrict__ degi, const int* __restrict__ blockoffs,
    int* __restrict__ row_start, int* __restrict__ cursor, int N) {
    __shared__ int tsum[SCAN_BLOCK];
    const int t = threadIdx.x;
    const int base = blockIdx.x * SCAN_TILE + t * SCAN_ELEMS;
    int v[SCAN_ELEMS];
    int s = 0;
#pragma unroll
    for (int i = 0; i < SCAN_ELEMS; ++i) {
        const int idx = base + i;
        v[i] = (idx < N) ? degi[idx] : 0;
        s += v[i];
    }
    tsum[t] = s;
    __syncthreads();
    for (int off = 1; off < SCAN_BLOCK; off <<= 1) {
        const int x = (t >= off) ? tsum[t - off] : 0;
        __syncthreads();
        tsum[t] += x;
        __syncthreads();
    }
    int excl = blockoffs[blockIdx.x] + tsum[t] - s;
#pragma unroll
    for (int i = 0; i < SCAN_ELEMS; ++i) {
        const int idx = base + i;
        if (idx < N) {
            row_start[idx] = excl;
            cursor[idx]    = excl;
        }
        excl += v[i];
    }
}

// Each thread owns 4 coalesced-stride edges; 4 independent returning atomics
// are issued back-to-back (one vmcnt drain for all 4), then 4 nontemporal
// scattered stores. Breaks the per-edge atomic->store latency chain.
__global__ void k_build(const int* __restrict__ src, const int* __restrict__ dst,
                        int* __restrict__ cursor, int* __restrict__ csr_src, int E) {
    const int gid    = blockIdx.x * blockDim.x + threadIdx.x;
    const int stride = gridDim.x * blockDim.x;
    int e[4], pos[4], sv[4];
    int cnt = 0;
#pragma unroll
    for (int i = 0; i < 4; ++i) {
        const int ee = gid + i * stride;
        if (ee < E) e[cnt++] = ee;
    }
#pragma unroll 4
    for (int i = 0; i < cnt; ++i)
        pos[i] = atomicAdd(&cursor[dst[e[i]]], 1);
#pragma unroll 4
    for (int i = 0; i < cnt; ++i)
        sv[i] = src[e[i]];
#pragma unroll 4
    for (int i = 0; i < cnt; ++i)
        __builtin_nontemporal_store(sv[i], &csr_src[pos[i]]);
}

// ---------------- conversions ----------------
__global__ void k_cvt_x(const float* __restrict__ x, const float* __restrict__ dinv,
                        unsigned short* __restrict__ xb, int Nrows, int Mp) {
    int i = blockIdx.x * blockDim.x + threadIdx.x;   // one thread per 4 elements
    int total = Mp * (NFEAT / 4);
    if (i >= total) return;
    int row = i / (NFEAT / 4);
    int q   = (i % (NFEAT / 4)) * 4;
    ushort4 o;
    if (row < Nrows) {
        const float w = dinv[row];
        const float4 v = *(const float4*)&x[(size_t)row * NFEAT + q];
        o.x = f2bf(v.x * w); o.y = f2bf(v.y * w);
        o.z = f2bf(v.z * w); o.w = f2bf(v.w * w);
    } else {
        o.x = 0; o.y = 0; o.z = 0; o.w = 0;
    }
    *(ushort4*)&xb[(size_t)row * NFEAT + q] = o;
}

__global__ void k_cvt_wt(const float* __restrict__ W, unsigned short* __restrict__ Wt,
                         int K, int Nc) {
    int i = blockIdx.x * blockDim.x + threadIdx.x;
    if (i >= K * Nc) return;
    int k = i / Nc, n = i % Nc;
    Wt[(size_t)n * K + k] = f2bf(W[(size_t)k * Nc + n]);
}

// ---------------- bf16 MFMA GEMM ----------------
__global__ __launch_bounds__(256) void gemm_bf16(
    const unsigned short* __restrict__ A, const unsigned short* __restrict__ Bt,
    unsigned short* __restrict__ C, int N, int K) {
    __shared__ unsigned short As[128 * 32];
    __shared__ unsigned short Bs[128 * 32];
    const int t    = threadIdx.x;
    const int wave = t >> 6, lane = t & 63;
    const int row0 = blockIdx.y * 128, col0 = blockIdx.x * 128;
    const int wm = (wave >> 1) * 64, wn = (wave & 1) * 64;
    const int sr = lane >> 2;
    const int sk = (lane & 3) * 8;
    const int quad = lane >> 4, l15 = lane & 15;

    const int ca = wave * 2;
    const unsigned short* gA0 = A  + (size_t)(row0 + ca * 16 + sr) * K + sk;
    const unsigned short* gA1 = gA0 + (size_t)16 * K;
    const unsigned short* gB0 = Bt + (size_t)(col0 + ca * 16 + sr) * K + sk;
    const unsigned short* gB1 = gB0 + (size_t)16 * K;
    unsigned short* lA0 = &As[ca * 512];
    unsigned short* lA1 = &As[(ca + 1) * 512];
    unsigned short* lB0 = &Bs[ca * 512];
    unsigned short* lB1 = &Bs[(ca + 1) * 512];

    float4v acc[4][4] = {};

    for (int k0 = 0; k0 < K; k0 += 32) {
        __syncthreads();
        load_lds16(gA0 + k0, lA0);
        load_lds16(gA1 + k0, lA1);
        load_lds16(gB0 + k0, lB0);
        load_lds16(gB1 + k0, lB1);
        __syncthreads();

        short8 a[4], b[4];
#pragma unroll
        for (int i = 0; i < 4; ++i) {
            a[i] = *(const short8*)&As[(wm + i * 16 + l15) * 32 + quad * 8];
            b[i] = *(const short8*)&Bs[(wn + i * 16 + l15) * 32 + quad * 8];
        }
#pragma unroll
        for (int mt = 0; mt < 4; ++mt)
#pragma unroll
            for (int nt = 0; nt < 4; ++nt)
                acc[mt][nt] = __builtin_amdgcn_mfma_f32_16x16x32_bf16(
                    a[mt], b[nt], acc[mt][nt], 0, 0, 0);
    }

    // C/D layout: col = lane&15, row = (lane>>4)*4 + reg   [m89-verified]
#pragma unroll
    for (int mt = 0; mt < 4; ++mt) {
#pragma unroll
        for (int nt = 0; nt < 4; ++nt) {
            const int c = col0 + wn + nt * 16 + l15;
#pragma unroll
            for (int r = 0; r < 4; ++r) {
                const int row = row0 + wm + mt * 16 + quad * 4 + r;
                C[(size_t)row * N + c] = f2bf(acc[mt][nt][r]);
            }
        }
    }
}

// ---------------- CSR gather aggregation (bf16 features, pre-scaled rows) ----
template <int F, bool RELU, bool OUTF32>
__global__ __launch_bounds__(256) void k_gather(
    const int* __restrict__ row_start, const int* __restrict__ csr_src,
    const float* __restrict__ dinv, const unsigned short* __restrict__ h,
    const float* __restrict__ bias, unsigned short* __restrict__ ob,
    float* __restrict__ of, int N) {
    const int gid  = blockIdx.x * blockDim.x + threadIdx.x;
    const int node = gid >> 6;
    const int lane = gid & 63;
    if (node >= N) return;

    constexpr int EL = F / 64;           // 4 (F=256) or 2 (F=128)
    const float wd = dinv[node];
    const int jb = row_start[node];
    const int je = row_start[node + 1];
    const unsigned short* hl = h + (size_t)lane * EL;

    float acc[EL];
    {   // self-loop term (h already dinv-scaled)
        const unsigned short* hp = hl + (size_t)node * F;
        if (EL == 4) {
            const ushort4 v = *(const ushort4*)hp;
            acc[0] = bf2f(v.x); acc[1] = bf2f(v.y);
            acc[2] = bf2f(v.z); acc[3] = bf2f(v.w);
        } else {
            const ushort2 v = *(const ushort2*)hp;
            acc[0] = bf2f(v.x); acc[1] = bf2f(v.y);
        }
    }

    for (int j0 = jb; j0 < je; j0 += 64) {
        int jj = j0 + lane;
        if (jj >= je) jj = je - 1;
        const int myi = csr_src[jj];
        const int rem = je - j0;
        const int cnt = rem < 64 ? rem : 64;
        int i = 0;
        for (; i + 4 <= cnt; i += 4) {   // 4 independent row loads in flight
            const int s0 = __shfl(myi, i + 0);
            const int s1 = __shfl(myi, i + 1);
            const int s2 = __shfl(myi, i + 2);
            const int s3 = __shfl(myi, i + 3);
            if (EL == 4) {
                const ushort4 v0 = *(const ushort4*)(hl + (size_t)s0 * F);
                const ushort4 v1 = *(const ushort4*)(hl + (size_t)s1 * F);
                const ushort4 v2 = *(const ushort4*)(hl + (size_t)s2 * F);
                const ushort4 v3 = *(const ushort4*)(hl + (size_t)s3 * F);
                acc[0] += bf2f(v0.x) + bf2f(v1.x) + bf2f(v2.x) + bf2f(v3.x);
                acc[1] += bf2f(v0.y) + bf2f(v1.y) + bf2f(v2.y) + bf2f(v3.y);
                acc[2] += bf2f(v0.z) + bf2f(v1.z) + bf2f(v2.z) + bf2f(v3.z);
                acc[3] += bf2f(v0.w) + bf2f(v1.w) + bf2f(v2.w) + bf2f(v3.w);
            } else {
                const ushort2 v0 = *(const ushort2*)(hl + (size_t)s0 * F);
                const ushort2 v1 = *(const ushort2*)(hl + (size_t)s1 * F);
                const ushort2 v2 = *(const ushort2*)(hl + (size_t)s2 * F);
                const ushort2 v3 = *(const ushort2*)(hl + (size_t)s3 * F);
                acc[0] += bf2f(v0.x) + bf2f(v1.x) + bf2f(v2.x) + bf2f(v3.x);
                acc[1] += bf2f(v0.y) + bf2f(v1.y) + bf2f(v2.y) + bf2f(v3.y);
            }
        }
        for (; i < cnt; ++i) {
            const int s = __shfl(myi, i);
            const unsigned short* hp = hl + (size_t)s * F;
            if (EL == 4) {
                const ushort4 v = *(const ushort4*)hp;
                acc[0] += bf2f(v.x); acc[1] += bf2f(v.y);
                acc[2] += bf2f(v.z); acc[3] += bf2f(v.w);
            } else {
                const ushort2 v = *(const ushort2*)hp;
                acc[0] += bf2f(v.x); acc[1] += bf2f(v.y);
            }
        }
    }

#pragma unroll
    for (int i = 0; i < EL; ++i) {
        float v = fmaf(acc[i], wd, bias[lane * EL + i]);
        if (OUTF32) {
            of[(size_t)node * F + lane * EL + i] = v;
        } else {
            if (RELU) v = fmaxf(v, 0.f);
            ob[(size_t)node * F + lane * EL + i] = f2bf(v * wd);  // pre-scale for next layer
        }
    }
}

extern "C" void kernel_launch(void* const* d_in, const int* in_sizes, int n_in,
                              void* d_out, int out_size, void* d_ws, size_t ws_size,
                              hipStream_t stream) {
    const float* x   = (const float*)d_in[0];
    const int*   ei  = (const int*)d_in[1];
    const float* W1  = (const float*)d_in[2];
    const float* b1  = (const float*)d_in[3];
    const float* W2  = (const float*)d_in[4];
    const float* b2  = (const float*)d_in[5];
    float*       out = (float*)d_out;

    const int N = in_sizes[0] / NFEAT;           // 50000
    const int E = in_sizes[1] / 2;               // 800000
    const int Mp = ((N + 127) / 128) * 128;      // 50048
    const int* srcp = ei;
    const int* dstp = ei + E;
    const int nScanBlocks = (N + SCAN_TILE - 1) / SCAN_TILE;   // 49

    // workspace layout (256B aligned chunks)
    char* wsb = (char*)d_ws;
    auto take = [&](size_t bytes) {
        char* p = wsb;
        wsb += (bytes + 255) & ~(size_t)255;
        return p;
    };
    int*   degi      = (int*)take((size_t)N * 4);
    int*   row_start = (int*)take((size_t)(N + 1) * 4);
    int*   cursor    = (int*)take((size_t)N * 4);
    int*   csr_src   = (int*)take((size_t)E * 4);
    int*   blocksums = (int*)take((size_t)1024 * 4);
    int*   blockoffs = (int*)take((size_t)1024 * 4);
    float* dinv      = (float*)take((size_t)N * 4);
    unsigned short* xb  = (unsigned short*)take((size_t)Mp * NFEAT * 2);  // also h2
    unsigned short* W1t = (unsigned short*)take((size_t)NH1 * NFEAT * 2);
    unsigned short* W2t = (unsigned short*)take((size_t)NH2 * NH1 * 2);
    unsigned short* h   = (unsigned short*)take((size_t)Mp * NH1 * 2);
    unsigned short* h1  = (unsigned short*)take((size_t)Mp * NH1 * 2);
    unsigned short* h2  = xb;                    // xb dead after GEMM1

    // ---- CSR build + dinv + conversions ----
    k_zero_int<<<(N + 255) / 256, 256, 0, stream>>>(degi, N);
    k_deg_int<<<1024, 256, 0, stream>>>(dstp, degi, E);
    k_dinv<<<(N + 255) / 256, 256, 0, stream>>>(degi, dinv, N);
    k_scan1<<<nScanBlocks, SCAN_BLOCK, 0, stream>>>(degi, blocksums, N);
    k_scan2<<<1, 1024, 0, stream>>>(blocksums, blockoffs, row_start, nScanBlocks, N);
    k_scan3<<<nScanBlocks, SCAN_BLOCK, 0, stream>>>(degi, blockoffs, row_start, cursor, N);
    {
        int threads = (E + 3) / 4;
        k_build<<<(threads + 255) / 256, 256, 0, stream>>>(srcp, dstp, cursor, csr_src, E);
    }
    {
        int total = Mp * (NFEAT / 4);
        k_cvt_x<<<(total + 255) / 256, 256, 0, stream>>>(x, dinv, xb, N, Mp);
    }
    k_cvt_wt<<<(NFEAT * NH1 + 255) / 256, 256, 0, stream>>>(W1, W1t, NFEAT, NH1);
    k_cvt_wt<<<(NH1 * NH2 + 255) / 256, 256, 0, stream>>>(W2, W2t, NH1, NH2);

    // ---- layer 1: h = (x*dinv)@W1 (bf16) ; h1 = relu(...)*dinv (bf16) ----
    {
        dim3 g(NH1 / 128, Mp / 128);
        gemm_bf16<<<g, 256, 0, stream>>>(xb, W1t, h, NH1, NFEAT);
    }
    {
        int total = N * 64;
        k_gather<NH1, true, false><<<(total + 255) / 256, 256, 0, stream>>>(
            row_start, csr_src, dinv, h, b1, h1, nullptr, N);
    }

    // ---- layer 2: h2 = h1s@W2 (bf16) ; out = gather + b2 (fp32) ----
    {
        dim3 g(NH2 / 128, Mp / 128);
        gemm_bf16<<<g, 256, 0, stream>>>(h1, W2t, h2, NH2, NH1);
    }
    {
        int total = N * 64;
        k_gather<NH2, false, true><<<(total + 255) / 256, 256, 0, stream>>>(
            row_start, csr_src, dinv, h2, b2, nullptr, out, N);
    }
}

// Round 8
// 372.086 us; speedup vs baseline: 10.1718x; 1.0916x over previous
//
#include <hip/hip_runtime.h>
#include <cstdint>
#include <cstddef>

#define NFEAT 512
#define NH1   256
#define NH2   128

#define SCAN_BLOCK 256
#define SCAN_ELEMS 4
#define SCAN_TILE  (SCAN_BLOCK * SCAN_ELEMS)   // 1024

#define P_CHUNKS 128          // edge chunks for privatized histogram
#define HHALF    25088        // nodes per half (2*HHALF = 50176 >= N)
#define NP       (2 * HHALF)  // padded node count in hist rows

typedef __attribute__((ext_vector_type(8))) short short8;
typedef __attribute__((ext_vector_type(4))) float float4v;

__device__ __forceinline__ unsigned short f2bf(float f) {
    unsigned int u = __float_as_uint(f);
    u += 0x7fffu + ((u >> 16) & 1u);   // round-to-nearest-even
    return (unsigned short)(u >> 16);
}
__device__ __forceinline__ float bf2f(unsigned short u) {
    return __uint_as_float(((unsigned int)u) << 16);
}

__device__ __forceinline__ void load_lds16(const void* g, void* l) {
    __builtin_amdgcn_global_load_lds(
        (const __attribute__((address_space(1))) void*)g,
        (__attribute__((address_space(3))) void*)l, 16, 0, 0);
}

// ---------------- CSR build: LDS-privatized counting sort ----------------
// Phase A: per-(chunk,half) histogram in LDS, coalesced write to hist[c][d].
__global__ __launch_bounds__(256) void k_hist(const int* __restrict__ dst,
                                              int* __restrict__ hist, int E, int CE) {
    __shared__ int lh[HHALF];
    const int c    = blockIdx.x >> 1;
    const int hf   = blockIdx.x & 1;
    const int base = hf * HHALF;
    for (int i = threadIdx.x; i < HHALF; i += 256) lh[i] = 0;
    __syncthreads();
    const int lo = c * CE;
    const int hi = lo + CE < E ? lo + CE : E;
    for (int e = lo + (int)threadIdx.x; e < hi; e += 256) {
        const int d = dst[e] - base;
        if ((unsigned)d < (unsigned)HHALF) atomicAdd(&lh[d], 1);
    }
    __syncthreads();
    int* outp = hist + (size_t)c * NP + base;
    for (int i = threadIdx.x; i < HHALF; i += 256) outp[i] = lh[i];
}

// Phase B: degi[d] = sum_c hist[c][d]; fused dinv = rsqrt(deg+1).
__global__ void k_colreduce(const int* __restrict__ hist, int* __restrict__ degi,
                            float* __restrict__ dinv, int N) {
    const int d = blockIdx.x * blockDim.x + threadIdx.x;
    if (d >= N) return;
    int s = 0;
#pragma unroll 8
    for (int c = 0; c < P_CHUNKS; ++c) s += hist[(size_t)c * NP + d];
    degi[d] = s;
    dinv[d] = rsqrtf((float)(s + 1));   // +1 = self-loop
}

// Phase D: in-place column exclusive scan: hist[c][d] -> global base offset.
__global__ void k_coloffs(int* __restrict__ hist, const int* __restrict__ row_start,
                          int N) {
    const int d = blockIdx.x * blockDim.x + threadIdx.x;
    if (d >= N) return;
    int run = row_start[d];
    for (int c = 0; c < P_CHUNKS; ++c) {
        int* p = &hist[(size_t)c * NP + d];
        const int t = *p;
        *p = run;
        run += t;
    }
}

// Phase E: place edges. LDS cursor atomics only; plain scattered stores.
__global__ __launch_bounds__(256) void k_place(const int* __restrict__ src,
                                               const int* __restrict__ dst,
                                               const int* __restrict__ hist,
                                               int* __restrict__ csr_src, int E, int CE) {
    __shared__ int lcur[HHALF];
    const int c    = blockIdx.x >> 1;
    const int hf   = blockIdx.x & 1;
    const int base = hf * HHALF;
    const int* offp = hist + (size_t)c * NP + base;
    for (int i = threadIdx.x; i < HHALF; i += 256) lcur[i] = offp[i];
    __syncthreads();
    const int lo = c * CE;
    const int hi = lo + CE < E ? lo + CE : E;
    for (int e = lo + (int)threadIdx.x; e < hi; e += 256) {
        const int d = dst[e] - base;
        if ((unsigned)d < (unsigned)HHALF) {
            const int p = atomicAdd(&lcur[d], 1);   // LDS atomic (fast)
            csr_src[p] = src[e];
        }
    }
}

// ---- three-phase exclusive scan over degi[0..N) -> row_start ----
__global__ __launch_bounds__(SCAN_BLOCK) void k_scan1(
    const int* __restrict__ degi, int* __restrict__ blocksums, int N) {
    __shared__ int red[SCAN_BLOCK];
    const int t = threadIdx.x;
    const int base = blockIdx.x * SCAN_TILE + t * SCAN_ELEMS;
    int s = 0;
#pragma unroll
    for (int i = 0; i < SCAN_ELEMS; ++i) {
        const int idx = base + i;
        if (idx < N) s += degi[idx];
    }
    red[t] = s;
    __syncthreads();
    for (int off = SCAN_BLOCK / 2; off > 0; off >>= 1) {
        if (t < off) red[t] += red[t + off];
        __syncthreads();
    }
    if (t == 0) blocksums[blockIdx.x] = red[0];
}

__global__ __launch_bounds__(1024) void k_scan2(
    const int* __restrict__ blocksums, int* __restrict__ blockoffs,
    int* __restrict__ row_start, int nb, int N) {
    __shared__ int sm[1024];
    const int t = threadIdx.x;
    const int v = (t < nb) ? blocksums[t] : 0;
    sm[t] = v;
    __syncthreads();
    for (int off = 1; off < 1024; off <<= 1) {
        const int x = (t >= off) ? sm[t - off] : 0;
        __syncthreads();
        sm[t] += x;
        __syncthreads();
    }
    if (t < nb) blockoffs[t] = sm[t] - v;
    if (t == 1023) row_start[N] = sm[1023];
}

__global__ __launch_bounds__(SCAN_BLOCK) void k_scan3(
    const int* __restrict__ degi, const int* __restrict__ blockoffs,
    int* __restrict__ row_start, int N) {
    __shared__ int tsum[SCAN_BLOCK];
    const int t = threadIdx.x;
    const int base = blockIdx.x * SCAN_TILE + t * SCAN_ELEMS;
    int v[SCAN_ELEMS];
    int s = 0;
#pragma unroll
    for (int i = 0; i < SCAN_ELEMS; ++i) {
        const int idx = base + i;
        v[i] = (idx < N) ? degi[idx] : 0;
        s += v[i];
    }
    tsum[t] = s;
    __syncthreads();
    for (int off = 1; off < SCAN_BLOCK; off <<= 1) {
        const int x = (t >= off) ? tsum[t - off] : 0;
        __syncthreads();
        tsum[t] += x;
        __syncthreads();
    }
    int excl = blockoffs[blockIdx.x] + tsum[t] - s;
#pragma unroll
    for (int i = 0; i < SCAN_ELEMS; ++i) {
        const int idx = base + i;
        if (idx < N) row_start[idx] = excl;
        excl += v[i];
    }
}

// ---------------- conversions ----------------
__global__ void k_cvt_x(const float* __restrict__ x, const float* __restrict__ dinv,
                        unsigned short* __restrict__ xb, int Nrows, int Mp) {
    int i = blockIdx.x * blockDim.x + threadIdx.x;   // one thread per 4 elements
    int total = Mp * (NFEAT / 4);
    if (i >= total) return;
    int row = i / (NFEAT / 4);
    int q   = (i % (NFEAT / 4)) * 4;
    ushort4 o;
    if (row < Nrows) {
        const float w = dinv[row];
        const float4 v = *(const float4*)&x[(size_t)row * NFEAT + q];
        o.x = f2bf(v.x * w); o.y = f2bf(v.y * w);
        o.z = f2bf(v.z * w); o.w = f2bf(v.w * w);
    } else {
        o.x = 0; o.y = 0; o.z = 0; o.w = 0;
    }
    *(ushort4*)&xb[(size_t)row * NFEAT + q] = o;
}

__global__ void k_cvt_wt(const float* __restrict__ W, unsigned short* __restrict__ Wt,
                         int K, int Nc) {
    int i = blockIdx.x * blockDim.x + threadIdx.x;
    if (i >= K * Nc) return;
    int k = i / Nc, n = i % Nc;
    Wt[(size_t)n * K + k] = f2bf(W[(size_t)k * Nc + n]);
}

// ---------------- bf16 MFMA GEMM ----------------
__global__ __launch_bounds__(256) void gemm_bf16(
    const unsigned short* __restrict__ A, const unsigned short* __restrict__ Bt,
    unsigned short* __restrict__ C, int N, int K) {
    __shared__ unsigned short As[128 * 32];
    __shared__ unsigned short Bs[128 * 32];
    const int t    = threadIdx.x;
    const int wave = t >> 6, lane = t & 63;
    const int row0 = blockIdx.y * 128, col0 = blockIdx.x * 128;
    const int wm = (wave >> 1) * 64, wn = (wave & 1) * 64;
    const int sr = lane >> 2;
    const int sk = (lane & 3) * 8;
    const int quad = lane >> 4, l15 = lane & 15;

    const int ca = wave * 2;
    const unsigned short* gA0 = A  + (size_t)(row0 + ca * 16 + sr) * K + sk;
    const unsigned short* gA1 = gA0 + (size_t)16 * K;
    const unsigned short* gB0 = Bt + (size_t)(col0 + ca * 16 + sr) * K + sk;
    const unsigned short* gB1 = gB0 + (size_t)16 * K;
    unsigned short* lA0 = &As[ca * 512];
    unsigned short* lA1 = &As[(ca + 1) * 512];
    unsigned short* lB0 = &Bs[ca * 512];
    unsigned short* lB1 = &Bs[(ca + 1) * 512];

    float4v acc[4][4] = {};

    for (int k0 = 0; k0 < K; k0 += 32) {
        __syncthreads();
        load_lds16(gA0 + k0, lA0);
        load_lds16(gA1 + k0, lA1);
        load_lds16(gB0 + k0, lB0);
        load_lds16(gB1 + k0, lB1);
        __syncthreads();

        short8 a[4], b[4];
#pragma unroll
        for (int i = 0; i < 4; ++i) {
            a[i] = *(const short8*)&As[(wm + i * 16 + l15) * 32 + quad * 8];
            b[i] = *(const short8*)&Bs[(wn + i * 16 + l15) * 32 + quad * 8];
        }
#pragma unroll
        for (int mt = 0; mt < 4; ++mt)
#pragma unroll
            for (int nt = 0; nt < 4; ++nt)
                acc[mt][nt] = __builtin_amdgcn_mfma_f32_16x16x32_bf16(
                    a[mt], b[nt], acc[mt][nt], 0, 0, 0);
    }

    // C/D layout: col = lane&15, row = (lane>>4)*4 + reg   [m89-verified]
#pragma unroll
    for (int mt = 0; mt < 4; ++mt) {
#pragma unroll
        for (int nt = 0; nt < 4; ++nt) {
            const int c = col0 + wn + nt * 16 + l15;
#pragma unroll
            for (int r = 0; r < 4; ++r) {
                const int row = row0 + wm + mt * 16 + quad * 4 + r;
                C[(size_t)row * N + c] = f2bf(acc[mt][nt][r]);
            }
        }
    }
}

// ---------------- CSR gather aggregation (bf16 features, pre-scaled rows) ----
template <int F, bool RELU, bool OUTF32>
__global__ __launch_bounds__(256) void k_gather(
    const int* __restrict__ row_start, const int* __restrict__ csr_src,
    const float* __restrict__ dinv, const unsigned short* __restrict__ h,
    const float* __restrict__ bias, unsigned short* __restrict__ ob,
    float* __restrict__ of, int N) {
    const int gid  = blockIdx.x * blockDim.x + threadIdx.x;
    const int node = gid >> 6;
    const int lane = gid & 63;
    if (node >= N) return;

    constexpr int EL = F / 64;           // 4 (F=256) or 2 (F=128)
    const float wd = dinv[node];
    const int jb = row_start[node];
    const int je = row_start[node + 1];
    const unsigned short* hl = h + (size_t)lane * EL;

    float acc[EL];
    {   // self-loop term (h already dinv-scaled)
        const unsigned short* hp = hl + (size_t)node * F;
        if (EL == 4) {
            const ushort4 v = *(const ushort4*)hp;
            acc[0] = bf2f(v.x); acc[1] = bf2f(v.y);
            acc[2] = bf2f(v.z); acc[3] = bf2f(v.w);
        } else {
            const ushort2 v = *(const ushort2*)hp;
            acc[0] = bf2f(v.x); acc[1] = bf2f(v.y);
        }
    }

    for (int j0 = jb; j0 < je; j0 += 64) {
        int jj = j0 + lane;
        if (jj >= je) jj = je - 1;
        const int myi = csr_src[jj];
        const int rem = je - j0;
        const int cnt = rem < 64 ? rem : 64;
        int i = 0;
        for (; i + 4 <= cnt; i += 4) {   // 4 independent row loads in flight
            const int s0 = __shfl(myi, i + 0);
            const int s1 = __shfl(myi, i + 1);
            const int s2 = __shfl(myi, i + 2);
            const int s3 = __shfl(myi, i + 3);
            if (EL == 4) {
                const ushort4 v0 = *(const ushort4*)(hl + (size_t)s0 * F);
                const ushort4 v1 = *(const ushort4*)(hl + (size_t)s1 * F);
                const ushort4 v2 = *(const ushort4*)(hl + (size_t)s2 * F);
                const ushort4 v3 = *(const ushort4*)(hl + (size_t)s3 * F);
                acc[0] += bf2f(v0.x) + bf2f(v1.x) + bf2f(v2.x) + bf2f(v3.x);
                acc[1] += bf2f(v0.y) + bf2f(v1.y) + bf2f(v2.y) + bf2f(v3.y);
                acc[2] += bf2f(v0.z) + bf2f(v1.z) + bf2f(v2.z) + bf2f(v3.z);
                acc[3] += bf2f(v0.w) + bf2f(v1.w) + bf2f(v2.w) + bf2f(v3.w);
            } else {
                const ushort2 v0 = *(const ushort2*)(hl + (size_t)s0 * F);
                const ushort2 v1 = *(const ushort2*)(hl + (size_t)s1 * F);
                const ushort2 v2 = *(const ushort2*)(hl + (size_t)s2 * F);
                const ushort2 v3 = *(const ushort2*)(hl + (size_t)s3 * F);
                acc[0] += bf2f(v0.x) + bf2f(v1.x) + bf2f(v2.x) + bf2f(v3.x);
                acc[1] += bf2f(v0.y) + bf2f(v1.y) + bf2f(v2.y) + bf2f(v3.y);
            }
        }
        for (; i < cnt; ++i) {
            const int s = __shfl(myi, i);
            const unsigned short* hp = hl + (size_t)s * F;
            if (EL == 4) {
                const ushort4 v = *(const ushort4*)hp;
                acc[0] += bf2f(v.x); acc[1] += bf2f(v.y);
                acc[2] += bf2f(v.z); acc[3] += bf2f(v.w);
            } else {
                const ushort2 v = *(const ushort2*)hp;
                acc[0] += bf2f(v.x); acc[1] += bf2f(v.y);
            }
        }
    }

#pragma unroll
    for (int i = 0; i < EL; ++i) {
        float v = fmaf(acc[i], wd, bias[lane * EL + i]);
        if (OUTF32) {
            of[(size_t)node * F + lane * EL + i] = v;
        } else {
            if (RELU) v = fmaxf(v, 0.f);
            ob[(size_t)node * F + lane * EL + i] = f2bf(v * wd);  // pre-scale for next layer
        }
    }
}

extern "C" void kernel_launch(void* const* d_in, const int* in_sizes, int n_in,
                              void* d_out, int out_size, void* d_ws, size_t ws_size,
                              hipStream_t stream) {
    const float* x   = (const float*)d_in[0];
    const int*   ei  = (const int*)d_in[1];
    const float* W1  = (const float*)d_in[2];
    const float* b1  = (const float*)d_in[3];
    const float* W2  = (const float*)d_in[4];
    const float* b2  = (const float*)d_in[5];
    float*       out = (float*)d_out;

    const int N = in_sizes[0] / NFEAT;           // 50000
    const int E = in_sizes[1] / 2;               // 800000
    const int Mp = ((N + 127) / 128) * 128;      // 50048
    const int* srcp = ei;
    const int* dstp = ei + E;
    const int nScanBlocks = (N + SCAN_TILE - 1) / SCAN_TILE;   // 49
    const int CE = (E + P_CHUNKS - 1) / P_CHUNKS;              // 6250

    // workspace layout (256B aligned chunks)
    char* wsb = (char*)d_ws;
    auto take = [&](size_t bytes) {
        char* p = wsb;
        wsb += (bytes + 255) & ~(size_t)255;
        return p;
    };
    int*   degi      = (int*)take((size_t)N * 4);
    int*   row_start = (int*)take((size_t)(N + 1) * 4);
    int*   csr_src   = (int*)take((size_t)E * 4);
    int*   blocksums = (int*)take((size_t)1024 * 4);
    int*   blockoffs = (int*)take((size_t)1024 * 4);
    float* dinv      = (float*)take((size_t)N * 4);
    unsigned short* xb  = (unsigned short*)take((size_t)Mp * NFEAT * 2);  // also h2
    unsigned short* W1t = (unsigned short*)take((size_t)NH1 * NFEAT * 2);
    unsigned short* W2t = (unsigned short*)take((size_t)NH2 * NH1 * 2);
    // union region: hist (25.7 MB, dead before GEMM1) overlaps h + h1 (51.2 MB)
    const size_t hBytes    = (size_t)Mp * NH1 * 2;
    const size_t histBytes = (size_t)P_CHUNKS * NP * 4;
    char* big = take(histBytes > 2 * hBytes ? histBytes : 2 * hBytes);
    int*            hist = (int*)big;
    unsigned short* h    = (unsigned short*)big;
    unsigned short* h1   = (unsigned short*)(big + hBytes);
    unsigned short* h2   = xb;                   // xb dead after GEMM1

    // ---- CSR build (atomic-free) + dinv ----
    k_hist<<<P_CHUNKS * 2, 256, 0, stream>>>(dstp, hist, E, CE);
    k_colreduce<<<(N + 255) / 256, 256, 0, stream>>>(hist, degi, dinv, N);
    k_scan1<<<nScanBlocks, SCAN_BLOCK, 0, stream>>>(degi, blocksums, N);
    k_scan2<<<1, 1024, 0, stream>>>(blocksums, blockoffs, row_start, nScanBlocks, N);
    k_scan3<<<nScanBlocks, SCAN_BLOCK, 0, stream>>>(degi, blockoffs, row_start, N);
    k_coloffs<<<(N + 255) / 256, 256, 0, stream>>>(hist, row_start, N);
    k_place<<<P_CHUNKS * 2, 256, 0, stream>>>(srcp, dstp, hist, csr_src, E, CE);

    // ---- conversions ----
    {
        int total = Mp * (NFEAT / 4);
        k_cvt_x<<<(total + 255) / 256, 256, 0, stream>>>(x, dinv, xb, N, Mp);
    }
    k_cvt_wt<<<(NFEAT * NH1 + 255) / 256, 256, 0, stream>>>(W1, W1t, NFEAT, NH1);
    k_cvt_wt<<<(NH1 * NH2 + 255) / 256, 256, 0, stream>>>(W2, W2t, NH1, NH2);

    // ---- layer 1: h = (x*dinv)@W1 (bf16) ; h1 = relu(...)*dinv (bf16) ----
    {
        dim3 g(NH1 / 128, Mp / 128);
        gemm_bf16<<<g, 256, 0, stream>>>(xb, W1t, h, NH1, NFEAT);
    }
    {
        int total = N * 64;
        k_gather<NH1, true, false><<<(total + 255) / 256, 256, 0, stream>>>(
            row_start, csr_src, dinv, h, b1, h1, nullptr, N);
    }

    // ---- layer 2: h2 = h1s@W2 (bf16) ; out = gather + b2 (fp32) ----
    {
        dim3 g(NH2 / 128, Mp / 128);
        gemm_bf16<<<g, 256, 0, stream>>>(h1, W2t, h2, NH2, NH1);
    }
    {
        int total = N * 64;
        k_gather<NH2, false, true><<<(total + 255) / 256, 256, 0, stream>>>(
            row_start, csr_src, dinv, h2, b2, nullptr, out, N);
    }
}